// Round 10
// baseline (1254.671 us; speedup 1.0000x reference)
//
#include <hip/hip_runtime.h>
#include <hip/hip_bf16.h>

#define HEADS 8
#define DH 64
#define EMB 512
#define NP 4352
#define NTOK 4097
#define PADF 255
#define LM 256
#define SCALE 0.125f

typedef __attribute__((ext_vector_type(8))) short bf8;
typedef __attribute__((ext_vector_type(4))) float f4;
typedef __attribute__((ext_vector_type(8))) unsigned short us8;
typedef __attribute__((ext_vector_type(4))) unsigned short us4;
typedef unsigned short u16;

__device__ __forceinline__ u16 f2b(float f){
  union { float f; unsigned u; } x; x.f = f;
  unsigned r = x.u + 0x7fffu + ((x.u>>16)&1u);
  return (u16)(r>>16);
}
__device__ __forceinline__ float b2f(u16 h){
  union { unsigned u; float f; } x; x.u = ((unsigned)h)<<16;
  return x.f;
}

__device__ __forceinline__ void gload_lds(const u16* g, u16* l){
  __builtin_amdgcn_global_load_lds((const __attribute__((address_space(1))) void*)g,
                                   (__attribute__((address_space(3))) void*)l, 16, 0, 0);
}

// ======== 128x128 NT bf16 GEMM, BK=32, global_load_lds staging ========
// MODE 0: fp32 store; MODE 2: bf16 store; MODE 3: fp32 C[gm-rowoff] += v (gm<rowoff dropped)
template<int MODE>
__global__ __launch_bounds__(256)
void k_g128(const u16* __restrict__ A, const u16* __restrict__ B,
            float* __restrict__ C, u16* __restrict__ C16,
            int K, int lda, int ldb, int ldc,
            long sAb, long sAh, long sBb, long sBh, long sCb, long sCh, int nh,
            float alpha, const float* __restrict__ bias, int relu, int rowoff)
{
  int z = blockIdx.z;
  const u16* Ab = A + (long)(z/nh)*sAb + (long)(z%nh)*sAh;
  const u16* Bb = B + (long)(z/nh)*sBb + (long)(z%nh)*sBh;
  long cb = (long)(z/nh)*sCb + (long)(z%nh)*sCh;
  int m0 = blockIdx.y*128, n0 = blockIdx.x*128;
  __shared__ u16 As[128*32];
  __shared__ u16 Bs[128*32];
  int tid=threadIdx.x, w=tid>>6, lane=tid&63, q=lane>>4, lr=lane&15;
  int wrow=(w>>1)*64, wcol=(w&1)*64;
  int srow = tid>>2, scol = (tid&3)*8;
  const u16* ga  = Ab + (long)(m0+srow)*lda + scol;
  const u16* ga2 = Ab + (long)(m0+64+srow)*lda + scol;
  const u16* gb  = Bb + (long)(n0+srow)*ldb + scol;
  const u16* gb2 = Bb + (long)(n0+64+srow)*ldb + scol;
  u16* la  = &As[srow*32 + scol];
  u16* la2 = &As[(64+srow)*32 + scol];
  u16* lb  = &Bs[srow*32 + scol];
  u16* lb2 = &Bs[(64+srow)*32 + scol];
  f4 acc[4][4] = {};
  for(int k0=0;k0<K;k0+=32){
    gload_lds(ga, la);  gload_lds(ga2, la2);
    gload_lds(gb, lb);  gload_lds(gb2, lb2);
    ga+=32; ga2+=32; gb+=32; gb2+=32;
    __syncthreads();
    bf8 af[4], bfr[4];
    #pragma unroll
    for(int r=0;r<4;r++) af[r]  = *(const bf8*)&As[(wrow + r*16 + lr)*32 + q*8];
    #pragma unroll
    for(int t=0;t<4;t++) bfr[t] = *(const bf8*)&Bs[(wcol + t*16 + lr)*32 + q*8];
    #pragma unroll
    for(int r=0;r<4;r++)
      #pragma unroll
      for(int t=0;t<4;t++)
        acc[r][t] = __builtin_amdgcn_mfma_f32_16x16x32_bf16(af[r], bfr[t], acc[r][t], 0,0,0);
    __syncthreads();
  }
  #pragma unroll
  for(int r=0;r<4;r++){
    #pragma unroll
    for(int t=0;t<4;t++){
      #pragma unroll
      for(int e=0;e<4;e++){
        int gm = m0 + wrow + r*16 + q*4 + e;
        int gn = n0 + wcol + t*16 + lr;
        float v = acc[r][t][e]*alpha;
        if(bias) v += bias[gn];
        if(relu) v = fmaxf(v,0.f);
        if(MODE==0) C[cb + (long)gm*ldc + gn] = v;
        else if(MODE==2) C16[cb + (long)gm*ldc + gn] = f2b(v);
        else { if(gm>=rowoff) C[cb + (long)(gm-rowoff)*ldc + gn] += v; }
      }
    }
  }
}

// ======== 64x64 NT bf16 GEMM, split-K capable, epilogue options ========
// MODE 0: fp32 store; MODE 1: fp32 C[gm-rowoff] += v (gm<rowoff dropped);
// MODE 2: bf16 store; MODE 3: fp32 atomicAdd
template<int MODE>
__global__ __launch_bounds__(256)
void k_g64(const u16* __restrict__ A, const u16* __restrict__ B,
           float* __restrict__ C, u16* __restrict__ C16,
           int K, int lda, int ldb, int ldc,
           long sAb, long sAh, long sBb, long sBh, long sCb, long sCh, int nh,
           float alpha, const float* __restrict__ bias, int relu, int rowoff,
           int nx, int ksplit)
{
  int z = blockIdx.z;
  const u16* Ab = A + (long)(z/nh)*sAb + (long)(z%nh)*sAh;
  const u16* Bb = B + (long)(z/nh)*sBb + (long)(z%nh)*sBh;
  long cb = (long)(z/nh)*sCb + (long)(z%nh)*sCh;
  int bx = blockIdx.x % nx, kc = blockIdx.x / nx;
  int m0 = blockIdx.y*64, n0 = bx*64;
  int klen = K/ksplit, kbeg = kc*klen;
  __shared__ u16 As[64*32];
  __shared__ u16 Bs[64*32];
  int tid=threadIdx.x, w=tid>>6, lane=tid&63, q=lane>>4, lr=lane&15;
  int srow = tid>>2, scol = (tid&3)*8;
  const u16* ga = Ab + (long)(m0+srow)*lda + kbeg + scol;
  const u16* gb = Bb + (long)(n0+srow)*ldb + kbeg + scol;
  u16* la = &As[srow*32 + scol];
  u16* lb = &Bs[srow*32 + scol];
  f4 acc[4] = {};
  for(int kk=0;kk<klen;kk+=32){
    gload_lds(ga, la); gload_lds(gb, lb);
    ga+=32; gb+=32;
    __syncthreads();
    bf8 af = *(const bf8*)&As[(w*16 + lr)*32 + q*8];
    #pragma unroll
    for(int t=0;t<4;t++){
      bf8 bfr = *(const bf8*)&Bs[(t*16 + lr)*32 + q*8];
      acc[t] = __builtin_amdgcn_mfma_f32_16x16x32_bf16(af, bfr, acc[t], 0,0,0);
    }
    __syncthreads();
  }
  #pragma unroll
  for(int t=0;t<4;t++){
    #pragma unroll
    for(int e=0;e<4;e++){
      int gm = m0 + w*16 + q*4 + e;
      int gn = n0 + t*16 + lr;
      float v = acc[t][e]*alpha;
      if(bias) v += bias[gn];
      if(relu) v = fmaxf(v,0.f);
      if(MODE==0) C[cb + (long)gm*ldc + gn] = v;
      else if(MODE==1){ if(gm>=rowoff) C[cb + (long)(gm-rowoff)*ldc + gn] += v; }
      else if(MODE==2) C16[cb + (long)gm*ldc + gn] = f2b(v);
      else atomicAdd(&C[cb + (long)gm*ldc + gn], v);
    }
  }
}

// ======== pinv GEMM on bf16 hi/lo pairs — 1-wave blocks, 16x64 strips ========
// S[m][n] = sum_k A[m][k]*B[n][k] (3-MFMA split). If Oh: Oh/Ol = na*S + nd*I.
// If TOh: TOh/TOl[gn][gm] = ta*S[gm][gn] + td*I.  grid (4, 16, 16), block 64.
__global__ __launch_bounds__(64)
void k_pg4(const u16* __restrict__ Ah, const u16* __restrict__ Al,
           const u16* __restrict__ Bh, const u16* __restrict__ Bl,
           u16* __restrict__ Oh, u16* __restrict__ Ol, float na, float nd,
           u16* __restrict__ TOh, u16* __restrict__ TOl, float ta, float td)
{
  long zo = (long)blockIdx.z*65536;
  int m0 = blockIdx.y*16, n0 = blockIdx.x*64;
  __shared__ u16 SA[2][2][512];    // [region][hi/lo][16x32]
  __shared__ u16 SB[2][2][2048];   // [region][hi/lo][64x32]
  int lane = threadIdx.x, q = lane>>4, lr = lane&15;
  int r4 = lane>>2, c8 = (lane&3)*8;
  f4 acc[4] = {};
  auto stage = [&](int rg, int c){
    long ab = zo + (long)(m0 + r4)*256 + c*32 + c8;
    gload_lds(Ah+ab, &SA[rg][0][r4*32 + c8]);
    gload_lds(Al+ab, &SA[rg][1][r4*32 + c8]);
    #pragma unroll
    for(int p=0;p<4;p++){
      long bb = zo + (long)(n0 + p*16 + r4)*256 + c*32 + c8;
      gload_lds(Bh+bb, &SB[rg][0][(p*16 + r4)*32 + c8]);
      gload_lds(Bl+bb, &SB[rg][1][(p*16 + r4)*32 + c8]);
    }
  };
  auto compute = [&](int rg){
    bf8 ah = *(const bf8*)&SA[rg][0][lr*32 + q*8];
    bf8 al = *(const bf8*)&SA[rg][1][lr*32 + q*8];
    #pragma unroll
    for(int t=0;t<4;t++){
      bf8 bh = *(const bf8*)&SB[rg][0][(t*16+lr)*32 + q*8];
      bf8 bl = *(const bf8*)&SB[rg][1][(t*16+lr)*32 + q*8];
      acc[t] = __builtin_amdgcn_mfma_f32_16x16x32_bf16(ah, bh, acc[t], 0,0,0);
      acc[t] = __builtin_amdgcn_mfma_f32_16x16x32_bf16(ah, bl, acc[t], 0,0,0);
      acc[t] = __builtin_amdgcn_mfma_f32_16x16x32_bf16(al, bh, acc[t], 0,0,0);
    }
  };
  stage(0,0);
  __syncthreads();
  #pragma unroll
  for(int c=1;c<8;c++){
    stage(c&1, c);
    compute((c-1)&1);
    __syncthreads();
  }
  compute(1);
  #pragma unroll
  for(int t=0;t<4;t++){
    int gn = n0 + t*16 + lr;
    if(Oh){
      #pragma unroll
      for(int r=0;r<4;r++){
        int gm = m0 + q*4 + r;
        float v = na*acc[t][r] + ((gm==gn)?nd:0.f);
        u16 h = f2b(v);
        long o = zo + (long)gm*256 + gn;
        Oh[o] = h; Ol[o] = f2b(v - b2f(h));
      }
    }
    if(TOh){
      us4 th, tl;
      #pragma unroll
      for(int r=0;r<4;r++){
        int gm = m0 + q*4 + r;
        float v = ta*acc[t][r] + ((gm==gn)?td:0.f);
        u16 h = f2b(v);
        th[r] = h; tl[r] = f2b(v - b2f(h));
      }
      long o = zo + (long)gn*256 + (m0 + q*4);
      *(us4*)&TOh[o] = th; *(us4*)&TOl[o] = tl;
    }
  }
}

// ======== softmax: wave per row, 256 cols ========
__global__ __launch_bounds__(256)
void k_smw32(float* __restrict__ X){
  long row = (long)blockIdx.x*4 + (threadIdx.x>>6);
  int lane = threadIdx.x & 63;
  float* p = X + row*256;
  float4 v = *(float4*)&p[lane*4];
  float m = fmaxf(fmaxf(v.x,v.y),fmaxf(v.z,v.w));
  for(int s=32;s;s>>=1) m = fmaxf(m, __shfl_xor(m, s));
  float e0=expf(v.x-m), e1=expf(v.y-m), e2=expf(v.z-m), e3=expf(v.w-m);
  float sum = e0+e1+e2+e3;
  for(int s=32;s;s>>=1) sum += __shfl_xor(sum, s);
  float inv = 1.f/sum;
  float4 o = {e0*inv, e1*inv, e2*inv, e3*inv};
  *(float4*)&p[lane*4] = o;
}

__global__ __launch_bounds__(256)
void k_smw16(u16* __restrict__ X){
  long row = (long)blockIdx.x*4 + (threadIdx.x>>6);
  int lane = threadIdx.x & 63;
  u16* p = X + row*256;
  us4 v = *(us4*)&p[lane*4];
  float f0=b2f(v[0]), f1=b2f(v[1]), f2=b2f(v[2]), f3=b2f(v[3]);
  float m = fmaxf(fmaxf(f0,f1),fmaxf(f2,f3));
  for(int s=32;s;s>>=1) m = fmaxf(m, __shfl_xor(m, s));
  float e0=expf(f0-m), e1=expf(f1-m), e2=expf(f2-m), e3=expf(f3-m);
  float sum = e0+e1+e2+e3;
  for(int s=32;s;s>>=1) sum += __shfl_xor(sum, s);
  float inv = 1.f/sum;
  us4 o = {f2b(e0*inv), f2b(e1*inv), f2b(e2*inv), f2b(e3*inv)};
  *(us4*)&p[lane*4] = o;
}

// ======== softmax: block per row, 4352 cols, register-resident ========
__global__ __launch_bounds__(256)
void k_smb16(u16* __restrict__ X){
  u16* p = X + (long)blockIdx.x*4352;
  int tid=threadIdx.x, lane=tid&63, w=tid>>6;
  __shared__ float xw[4], sw[4];
  float e[17];
  float m = -1e30f;
  #pragma unroll
  for(int i=0;i<17;i++){ e[i] = b2f(p[tid + i*256]); m = fmaxf(m, e[i]); }
  for(int s=32;s;s>>=1) m = fmaxf(m, __shfl_xor(m, s));
  if(lane==0) xw[w] = m;
  __syncthreads();
  m = fmaxf(fmaxf(xw[0],xw[1]), fmaxf(xw[2],xw[3]));
  float sum = 0.f;
  #pragma unroll
  for(int i=0;i<17;i++){ e[i] = expf(e[i]-m); sum += e[i]; }
  for(int s=32;s;s>>=1) sum += __shfl_xor(sum, s);
  if(lane==0) sw[w] = sum;
  __syncthreads();
  sum = sw[0]+sw[1]+sw[2]+sw[3];
  float inv = 1.f/sum;
  #pragma unroll
  for(int i=0;i<17;i++) p[tid + i*256] = f2b(e[i]*inv);
}

// weight transpose+convert: in fp32 [K][N] -> out bf16 [N][K]
__global__ void k_wT(const float* __restrict__ in, u16* __restrict__ out, int K, int N){
  int n0=blockIdx.x*32, k0=blockIdx.y*32, tid=threadIdx.x;
  __shared__ float T[32][33];
  int lr=tid&31, lc=tid>>5;
  #pragma unroll
  for(int p=0;p<4;p++) T[lc+8*p][lr] = in[(long)(k0+lc+8*p)*N + n0+lr];
  __syncthreads();
  #pragma unroll
  for(int p=0;p<4;p++) out[(long)(n0+lc+8*p)*K + k0+lr] = f2b(T[lr][lc+8*p]);
}

// v^T: qkvb16 v-section [NP][64] per (b,h) -> vT [b][h][64][NP]
__global__ __launch_bounds__(256)
void k_vT(const u16* __restrict__ qkv16, u16* __restrict__ vT){
  int t0=blockIdx.x*64, h=blockIdx.y, b=blockIdx.z, tid=threadIdx.x;
  __shared__ u16 T[64][72];
  const u16* src = qkv16 + (long)b*NP*1536 + 1024 + h*64;
  for(int s=0;s<2;s++){
    int idx=tid+s*256; int row=idx>>3, c8=(idx&7)*8;
    *(us8*)&T[row][c8] = *(const us8*)&src[(long)(t0+row)*1536 + c8];
  }
  __syncthreads();
  u16* dst = vT + ((long)(b*8+h)*64)*NP;
  int d = tid>>2, j0=(tid&3)*16;
  us8 v0,v1;
  #pragma unroll
  for(int jj=0;jj<8;jj++){ v0[jj]=T[j0+jj][d]; v1[jj]=T[j0+8+jj][d]; }
  *(us8*)&dst[(long)d*NP + t0 + j0]     = v0;
  *(us8*)&dst[(long)d*NP + t0 + j0 + 8] = v1;
}

__global__ void k_cvt16(const float* __restrict__ in, u16* __restrict__ out, long n){
  long i = (long)blockIdx.x*256 + threadIdx.x;
  if(i<n) out[i] = f2b(in[i]);
}

__global__ void k_zero(float* __restrict__ p, long n){
  long i = (long)blockIdx.x*256 + threadIdx.x;
  if(i<n) p[i] = 0.f;
}

__global__ void k_cls(const float* __restrict__ cls, float* __restrict__ seq){
  int b = blockIdx.x;
  seq[(long)b*NTOK*EMB + threadIdx.x] = cls[threadIdx.x];
}

// LayerNorm of seq into xpb bf16 with 255 zero rows at front
__global__ void k_ln_pad(const float* __restrict__ seq, u16* __restrict__ xp,
                         const float* __restrict__ g, const float* __restrict__ bb){
  int b = blockIdx.y, i = blockIdx.x, tid = threadIdx.x;
  u16* out = xp + ((long)b*NP + i)*EMB;
  if(i < PADF){ out[tid]=0; out[tid+256]=0; return; }
  const float* x = seq + ((long)b*NTOK + (i-PADF))*EMB;
  float v0 = x[tid], v1 = x[tid+256];
  __shared__ float red[256];
  red[tid]=v0+v1; __syncthreads();
  for(int s=128;s>0;s>>=1){ if(tid<s) red[tid]+=red[tid+s]; __syncthreads(); }
  float mu = red[0]*(1.0f/512.0f); __syncthreads();
  float d0=v0-mu, d1=v1-mu;
  red[tid]=d0*d0+d1*d1; __syncthreads();
  for(int s=128;s>0;s>>=1){ if(tid<s) red[tid]+=red[tid+s]; __syncthreads(); }
  float rstd = rsqrtf(red[0]*(1.0f/512.0f) + 1e-5f);
  out[tid]     = f2b(d0*rstd*g[tid]     + bb[tid]);
  out[tid+256] = f2b(d1*rstd*g[tid+256] + bb[tid+256]);
}

__global__ void k_landmarks(const u16* __restrict__ qkv, u16* __restrict__ q_l, u16* __restrict__ k_l){
  int j = blockIdx.x, h = blockIdx.y, b = blockIdx.z, d = threadIdx.x;
  const u16* base = qkv + (long)b*NP*1536 + h*64 + d;
  float sq=0.f, sk=0.f;
  for(int l=0;l<17;l++){
    long row = (long)(j*17+l)*1536;
    sq += b2f(base[row]);
    sk += b2f(base[row+512]);
  }
  long o = (((long)b*HEADS + h)*LM + j)*DH + d;
  q_l[o] = f2b(sq * (SCALE/17.0f));
  k_l[o] = f2b(sk * (1.0f/17.0f));
}

__global__ void k_pinv_norm(const float* __restrict__ A2, float* __restrict__ rmax, float* __restrict__ cmax){
  int z = blockIdx.x, tid = threadIdx.x;
  const float* X = A2 + (long)z*65536;
  float rs=0.f, cs=0.f;
  for(int j=0;j<256;j++){ rs += fabsf(X[tid*256+j]); cs += fabsf(X[j*256+tid]); }
  __shared__ float r1[256], r2[256];
  r1[tid]=rs; r2[tid]=cs; __syncthreads();
  for(int s=128;s>0;s>>=1){ if(tid<s){ r1[tid]=fmaxf(r1[tid],r1[tid+s]); r2[tid]=fmaxf(r2[tid],r2[tid+s]); } __syncthreads(); }
  if(tid==0){ rmax[z]=r1[0]; cmax[z]=r2[0]; }
}

__global__ void k_pair_init(const float* __restrict__ att2,
    const float* __restrict__ rmax, const float* __restrict__ cmax,
    u16* __restrict__ Xh, u16* __restrict__ Xl,
    u16* __restrict__ Zh, u16* __restrict__ Zl,
    u16* __restrict__ Zth, u16* __restrict__ Ztl)
{
  long zo = (long)blockIdx.z*65536;
  int i0 = blockIdx.y*64, j0 = blockIdx.x*64;
  float rm=0.f, cm=0.f;
  for(int t=0;t<16;t++){ rm=fmaxf(rm,rmax[t]); cm=fmaxf(cm,cmax[t]); }
  float inv = 1.0f/(rm*cm);
  __shared__ float T[64][68];
  int tid = threadIdx.x;
  int li = tid>>2, jc = (tid&3)*16;
  #pragma unroll
  for(int u=0;u<4;u++){
    float4 v = *(const float4*)&att2[zo + (long)(i0+li)*256 + j0 + jc + u*4];
    T[li][jc+u*4]=v.x; T[li][jc+u*4+1]=v.y; T[li][jc+u*4+2]=v.z; T[li][jc+u*4+3]=v.w;
    long o = zo + (long)(i0+li)*256 + j0 + jc + u*4;
    float vv[4] = {v.x,v.y,v.z,v.w};
    us4 xh, xl, zth, ztl;
    #pragma unroll
    for(int c=0;c<4;c++){
      u16 h = f2b(vv[c]); xh[c]=h; xl[c]=f2b(vv[c]-b2f(h));
      float zt = vv[c]*inv;
      u16 h2 = f2b(zt); zth[c]=h2; ztl[c]=f2b(zt-b2f(h2));
    }
    *(us4*)&Xh[o]=xh; *(us4*)&Xl[o]=xl; *(us4*)&Zth[o]=zth; *(us4*)&Ztl[o]=ztl;
  }
  __syncthreads();
  int lj = tid>>2, ic = (tid&3)*16;
  #pragma unroll
  for(int r=0;r<16;r++){
    float x = T[ic+r][lj]*inv;
    u16 h = f2b(x);
    long o = zo + (long)(j0+lj)*256 + i0 + ic + r;
    Zh[o]=h; Zl[o]=f2b(x-b2f(h));
  }
}

// res conv + fused bf16 convert: Qc16 = bf16(Qc + dwconv(v))
__global__ __launch_bounds__(256)
void k_rconv(const u16* __restrict__ qkv16, const float* __restrict__ resk,
             const float* __restrict__ Qin, u16* __restrict__ Qo16){
  int t0 = blockIdx.x*64, h = blockIdx.y, b = blockIdx.z;
  __shared__ float V[96*64];
  const u16* vb = qkv16 + (long)b*NP*1536 + 1024 + h*64;
  int tid = threadIdx.x;
  #pragma unroll
  for(int s=0;s<3;s++){
    int idx = tid + s*256;
    int row = idx>>3, c8 = (idx&7)*8;
    int p = t0 - 16 + row;
    if(p>=0 && p<NP){
      us8 v = *(const us8*)&vb[(long)p*1536 + c8];
      #pragma unroll
      for(int jj=0;jj<8;jj++) V[row*64+c8+jj] = b2f(v[jj]);
    } else {
      #pragma unroll
      for(int jj=0;jj<8;jj++) V[row*64+c8+jj] = 0.f;
    }
  }
  __syncthreads();
  int d = tid&63, lt = (tid>>6)*16;
  float acc[16] = {};
  #pragma unroll
  for(int s=0;s<48;s++){
    float val = V[(lt+s)*64 + d];
    #pragma unroll
    for(int j=0;j<16;j++){
      int tap = s - j;
      if(tap>=0 && tap<33) acc[j] += resk[h*33+tap]*val;
    }
  }
  #pragma unroll
  for(int j=0;j<16;j++){
    long idx = ((long)b*NP + t0 + lt + j)*EMB + h*64 + d;
    Qo16[idx] = f2b(Qin[idx] + acc[j]);
  }
}

// PPEG: 64-ch groups, 4 rows x 64 ch per block, x-split 2; grid (32, 8, 2)
__global__ __launch_bounds__(256)
void k_ppeg(const float* __restrict__ seq, float* __restrict__ out,
    const float* __restrict__ w7,const float* __restrict__ b7,
    const float* __restrict__ w5,const float* __restrict__ b5,
    const float* __restrict__ w3,const float* __restrict__ b3){
  int b = blockIdx.z, cg = blockIdx.y;
  int rp = blockIdx.x>>1, xs = blockIdx.x&1;
  int ch0 = cg*64;
  __shared__ float s7[64*49], s5[64*25], s3[64*9], sbias[64];
  int tid = threadIdx.x;
  for(int i=tid;i<64*49;i+=256) s7[i] = w7[ch0*49+i];
  for(int i=tid;i<64*25;i+=256) s5[i] = w5[ch0*25+i];
  for(int i=tid;i<64*9;i+=256)  s3[i] = w3[ch0*9+i];
  if(tid<64) sbias[tid] = b7[ch0+tid]+b5[ch0+tid]+b3[ch0+tid];
  if(cg==0 && blockIdx.x==0){
    out[(long)b*NTOK*EMB + tid]       = seq[(long)b*NTOK*EMB + tid];
    out[(long)b*NTOK*EMB + 256 + tid] = seq[(long)b*NTOK*EMB + 256 + tid];
  }
  __syncthreads();
  int c = tid & 63;
  int y = rp*4 + (tid>>6);
  const float* sbase = seq + (long)b*NTOK*EMB + EMB + (ch0 + c);
  float* obase = out + (long)b*NTOK*EMB + EMB + (ch0 + c);
  const float* W7 = &s7[c*49];
  const float* W5 = &s5[c*25];
  const float* W3 = &s3[c*9];
  float bsum = sbias[c];
  for(int xc=0;xc<4;xc++){
    int xb = xs*32 + xc*8;
    float acc[8];
    #pragma unroll
    for(int j=0;j<8;j++) acc[j] = sbase[(long)(y*64+xb+j)*EMB] + bsum;
    #pragma unroll
    for(int dy=-3;dy<=3;dy++){
      int yy = y+dy;
      if(yy<0||yy>=64) continue;
      float v[14];
      #pragma unroll
      for(int u=0;u<14;u++){
        int xx = xb + u - 3;
        v[u] = (xx>=0 && xx<64) ? sbase[(long)(yy*64+xx)*EMB] : 0.f;
      }
      #pragma unroll
      for(int dx=-3;dx<=3;dx++){
        float wsum = W7[(dy+3)*7+(dx+3)];
        if(dy>=-2&&dy<=2&&dx>=-2&&dx<=2) wsum += W5[(dy+2)*5+(dx+2)];
        if(dy>=-1&&dy<=1&&dx>=-1&&dx<=1) wsum += W3[(dy+1)*3+(dx+1)];
        #pragma unroll
        for(int j=0;j<8;j++) acc[j] += v[j+dx+3]*wsum;
      }
    }
    #pragma unroll
    for(int j=0;j<8;j++) obase[(long)(y*64+xb+j)*EMB] = acc[j];
  }
}

__global__ void k_final_ln(const float* __restrict__ seq, const float* __restrict__ g,
                           const float* __restrict__ bb, float* __restrict__ out){
  int b = blockIdx.x, tid = threadIdx.x;
  const float* x = seq + (long)b*NTOK*EMB;
  float v0 = x[tid], v1 = x[tid+256];
  __shared__ float red[256];
  red[tid]=v0+v1; __syncthreads();
  for(int s=128;s>0;s>>=1){ if(tid<s) red[tid]+=red[tid+s]; __syncthreads(); }
  float mu = red[0]*(1.0f/512.0f); __syncthreads();
  float d0=v0-mu, d1=v1-mu;
  red[tid]=d0*d0+d1*d1; __syncthreads();
  for(int s=128;s>0;s>>=1){ if(tid<s) red[tid]+=red[tid+s]; __syncthreads(); }
  float rstd = rsqrtf(red[0]*(1.0f/512.0f) + 1e-5f);
  out[b*512+tid]     = d0*rstd*g[tid]     + bb[tid];
  out[b*512+tid+256] = d1*rstd*g[tid+256] + bb[tid+256];
}

// ---------------- host ----------------
extern "C" void kernel_launch(void* const* d_in, const int* in_sizes, int n_in,
                              void* d_out, int out_size, void* d_ws, size_t ws_size,
                              hipStream_t stream) {
  const float* in[24];
  for(int i=0;i<24;i++) in[i] = (const float*)d_in[i];

  float* W = (float*)d_ws;
  size_t off = 0;
  float* seqA = W+off; off += 4195328;        // 2*4097*512
  float* seqB = W+off; off += 4195328;
  float* att2 = W+off; off += 1048576;        // 16*65536
  float* Qc   = W+off; off += 4456448;        // 2*4352*512
  float* avbT = W+off; off += 262144;         // 16*64*256
  u16* xpb    = (u16*)(W+off); off += 2228224;  // 2*4352*512 u16
  u16* qkvb16 = (u16*)(W+off); off += 6684672;  // 2*4352*1536 u16
  u16* vT16   = (u16*)(W+off); off += 2228224;
  u16* q_l16  = (u16*)(W+off); off += 131072;   // 16*256*64 u16
  u16* k_l16  = (u16*)(W+off); off += 131072;
  u16* sc16   = (u16*)(W+off); off += 8912896;  // 16*256*4352 u16
  u16* avbT16 = (u16*)(W+off); off += 131072;
  u16* zavT16 = (u16*)(W+off); off += 131072;
  u16* Qc16   = (u16*)(W+off); off += 2228224;
  u16* qkvwT1 = (u16*)(W+off); off += 393216;   // 1536*512 u16
  u16* qkvwT2 = (u16*)(W+off); off += 393216;
  u16* outwT1 = (u16*)(W+off); off += 131072;   // 512*512 u16
  u16* outwT2 = (u16*)(W+off); off += 131072;
  u16* pairs  = (u16*)(W+off); off += 9437184;  // 18*16*65536 u16
  float* rmax = W+off; off += 16;
  float* cmax = W+off; off += 16;
  if (ws_size < off*sizeof(float)) return;

  // h16 + wfc1T aliased inside sc16 (sc16 first written later, in attention())
  u16* h16   = sc16;                  // 8388608 u16
  u16* wfc1T = sc16 + 8388608;        // 524288 u16

  const long PB = 1048576;  // 16*65536
  u16 *Xh=pairs, *Xl=pairs+PB;
  u16 *Z0h=pairs+2*PB, *Z0l=pairs+3*PB, *Z0th=pairs+4*PB, *Z0tl=pairs+5*PB;
  u16 *Z1h=pairs+6*PB, *Z1l=pairs+7*PB, *Z1th=pairs+8*PB, *Z1tl=pairs+9*PB;
  u16 *Ph=pairs+10*PB, *Pl=pairs+11*PB;
  u16 *Tth=pairs+12*PB, *Ttl=pairs+13*PB;
  u16 *Uth=pairs+14*PB, *Utl=pairs+15*PB;
  u16 *Vth=pairs+16*PB, *Vtl=pairs+17*PB;

  // weight conversions/transposes
  k_cvt16<<<32768,256,0,stream>>>(in[0], h16, 8388608L);
  k_wT<<<dim3(16,32),256,0,stream>>>(in[1],  wfc1T, 1024, 512);
  k_wT<<<dim3(48,16),256,0,stream>>>(in[6],  qkvwT1, 512, 1536);
  k_wT<<<dim3(48,16),256,0,stream>>>(in[18], qkvwT2, 512, 1536);
  k_wT<<<dim3(16,16),256,0,stream>>>(in[7],  outwT1, 512, 512);
  k_wT<<<dim3(16,16),256,0,stream>>>(in[19], outwT2, 512, 512);

  // fc1 + cls (64-tile: 1024 blocks)
  k_g64<0><<<dim3(8,64,2),256,0,stream>>>(h16, wfc1T, seqA+EMB, nullptr,
      1024, 1024,1024,512, 4194304L,0, 0,0, (long)NTOK*EMB,0, 1, 1.0f, in[2], 1, 0, 8, 1);
  k_cls<<<2,512,0,stream>>>(in[3], seqA);

  auto attention = [&](float* seq, const float* lng,const float* lnb,
                       const u16* qkvwT, const u16* outwT, const float* outb, const float* resk){
    k_ln_pad<<<dim3(NP,2),256,0,stream>>>(seq, xpb, lng, lnb);
    k_g128<2><<<dim3(12,34,2),256,0,stream>>>(xpb, qkvwT, nullptr, qkvb16,
        512, 512,512,1536, (long)NP*512,0, 0,0, (long)NP*1536,0, 1, 1.0f, nullptr, 0, 0);
    k_landmarks<<<dim3(LM,HEADS,2),64,0,stream>>>(qkvb16, q_l16, k_l16);
    k_vT<<<dim3(68,8,2),256,0,stream>>>(qkvb16, vT16);
    // attn2 = softmax(q_l @ k_l^T)  (fp32 scores for pinv; 256 blocks)
    k_g64<0><<<dim3(4,4,16),256,0,stream>>>(q_l16, k_l16, att2, nullptr,
        64, 64,64,256, 0,16384, 0,16384, 0,65536, 16, 1.0f, nullptr, 0, 0, 4, 1);
    k_smw32<<<1024,256,0,stream>>>(att2);
    // pinv on bf16 pairs
    k_pinv_norm<<<16,256,0,stream>>>(att2, rmax, cmax);
    k_pair_init<<<dim3(4,4,16),256,0,stream>>>(att2, rmax, cmax, Xh,Xl, Z0h,Z0l, Z0th,Z0tl);
    dim3 pgrid(4,16,16);
    for(int it=0; it<6; it++){
      u16 *Zh_=(it&1)?Z1h:Z0h, *Zl_=(it&1)?Z1l:Z0l, *Zth_=(it&1)?Z1th:Z0th, *Ztl_=(it&1)?Z1tl:Z0tl;
      u16 *Nh_=(it&1)?Z0h:Z1h, *Nl_=(it&1)?Z0l:Z1l, *Nth_=(it&1)?Z0th:Z1th, *Ntl_=(it&1)?Z0tl:Z1tl;
      // P = X@Z (normal) ; Tt = (7I - P)^T (transposed)
      k_pg4<<<pgrid,64,0,stream>>>(Xh,Xl, Zth_,Ztl_, Ph,Pl,1.0f,0.f, Tth,Ttl,-1.0f,7.f);
      // Ut = (15I - P@T)^T
      k_pg4<<<pgrid,64,0,stream>>>(Ph,Pl, Tth,Ttl, nullptr,nullptr,0.f,0.f, Uth,Utl,-1.0f,15.f);
      // Vt = (13I - P@U)^T
      k_pg4<<<pgrid,64,0,stream>>>(Ph,Pl, Uth,Utl, nullptr,nullptr,0.f,0.f, Vth,Vtl,-1.0f,13.f);
      // Znew = 0.25 Z@V (normal; + transposed except last iter)
      if(it<5) k_pg4<<<pgrid,64,0,stream>>>(Zh_,Zl_, Vth,Vtl, Nh_,Nl_,0.25f,0.f, Nth_,Ntl_,0.25f,0.f);
      else     k_pg4<<<pgrid,64,0,stream>>>(Zh_,Zl_, Vth,Vtl, Nh_,Nl_,0.25f,0.f, nullptr,nullptr,0.f,0.f);
    }
    // attn3 scores = q_l @ k^T -> sc16 (bf16)
    k_g128<2><<<dim3(34,2,16),256,0,stream>>>(q_l16, qkvb16+512, nullptr, sc16,
        64, 64,1536,4352, 131072L,16384, (long)NP*1536,64, 8L*LM*NP,(long)LM*NP, 8, 1.0f, nullptr, 0, 0);
    k_smb16<<<4096,256,0,stream>>>(sc16);
    // avbT = v^T @ attn3_sm^T (split-K atomic)
    k_zero<<<1024,256,0,stream>>>(avbT, 262144L);
    k_g64<3><<<dim3(4*17,1,16),256,0,stream>>>(vT16, sc16, avbT, nullptr,
        4352, 4352,4352,256, 2228224L,278528L, 8L*LM*NP,(long)LM*NP, 131072L,16384L, 8, 1.0f, nullptr, 0, 0, 4, 17);
    k_cvt16<<<1024,256,0,stream>>>(avbT, avbT16, 262144L);
    // zavT = avbT @ Z^T  -> bf16
    k_g64<2><<<dim3(4,1,16),256,0,stream>>>(avbT16, Z0h, nullptr, zavT16,
        256, 256,256,256, 0,16384L, 0,65536L, 0,16384L, 16, 1.0f, nullptr, 0, 0, 4, 1);
    // attn1 scores = SCALE * q @ k_l^T -> sc16
    k_g128<2><<<dim3(2,34,16),256,0,stream>>>(qkvb16, k_l16, nullptr, sc16,
        64, 1536,64,256, (long)NP*1536,64, 131072L,16384L, 8L*NP*LM,(long)NP*LM, 8, SCALE, nullptr, 0, 0);
    k_smw16<<<17408,256,0,stream>>>(sc16);
    // Qc = attn1_sm @ zav   (per-head 64-col blocks)
    k_g64<0><<<dim3(1,68,16),256,0,stream>>>(sc16, zavT16, Qc, nullptr,
        256, 256,256,512, 8L*NP*LM,(long)NP*LM, 131072L,16384L, (long)NP*512,64, 8, 1.0f, nullptr, 0, 0, 1, 1);
    // res conv fused with bf16 convert
    k_rconv<<<dim3(68,8,2),256,0,stream>>>(qkvb16, resk, Qc, Qc16);
    // out proj + residual add into seq (64-tile: 1088 blocks)
    k_g64<1><<<dim3(8,68,2),256,0,stream>>>(Qc16, outwT, seq, nullptr,
        512, 512,512,512, (long)NP*512,0, 0,0, (long)NTOK*EMB,0, 1, 1.0f, outb, 0, PADF, 8, 1);
  };

  attention(seqA, in[4], in[5], qkvwT1, outwT1, in[8], in[9]);
  k_ppeg<<<dim3(32,8,2),256,0,stream>>>(seqA, seqB, in[10],in[11],in[12],in[13],in[14],in[15]);
  attention(seqB, in[16], in[17], qkvwT2, outwT2, in[20], in[21]);
  k_final_ln<<<2,256,0,stream>>>(seqB, in[22], in[23], (float*)d_out);
}

// Round 11
// 1102.535 us; speedup vs baseline: 1.1380x; 1.1380x over previous
//
#include <hip/hip_runtime.h>
#include <hip/hip_bf16.h>

#define HEADS 8
#define DH 64
#define EMB 512
#define NP 4352
#define NTOK 4097
#define PADF 255
#define LM 256
#define SCALE 0.125f

typedef __attribute__((ext_vector_type(8))) short bf8;
typedef __attribute__((ext_vector_type(4))) float f4;
typedef __attribute__((ext_vector_type(8))) unsigned short us8;
typedef __attribute__((ext_vector_type(4))) unsigned short us4;
typedef unsigned short u16;

__device__ __forceinline__ u16 f2b(float f){
  union { float f; unsigned u; } x; x.f = f;
  unsigned r = x.u + 0x7fffu + ((x.u>>16)&1u);
  return (u16)(r>>16);
}
__device__ __forceinline__ float b2f(u16 h){
  union { unsigned u; float f; } x; x.u = ((unsigned)h)<<16;
  return x.f;
}

__device__ __forceinline__ void gload_lds(const u16* g, u16* l){
  __builtin_amdgcn_global_load_lds((const __attribute__((address_space(1))) void*)g,
                                   (__attribute__((address_space(3))) void*)l, 16, 0, 0);
}

// ======== 128x128 NT bf16 GEMM, BK=32, global_load_lds staging ========
// MODE 0: fp32 store; MODE 2: bf16 store; MODE 3: fp32 C[gm-rowoff] += v (gm<rowoff dropped)
template<int MODE>
__global__ __launch_bounds__(256)
void k_g128(const u16* __restrict__ A, const u16* __restrict__ B,
            float* __restrict__ C, u16* __restrict__ C16,
            int K, int lda, int ldb, int ldc,
            long sAb, long sAh, long sBb, long sBh, long sCb, long sCh, int nh,
            float alpha, const float* __restrict__ bias, int relu, int rowoff)
{
  int z = blockIdx.z;
  const u16* Ab = A + (long)(z/nh)*sAb + (long)(z%nh)*sAh;
  const u16* Bb = B + (long)(z/nh)*sBb + (long)(z%nh)*sBh;
  long cb = (long)(z/nh)*sCb + (long)(z%nh)*sCh;
  int m0 = blockIdx.y*128, n0 = blockIdx.x*128;
  __shared__ u16 As[128*32];
  __shared__ u16 Bs[128*32];
  int tid=threadIdx.x, w=tid>>6, lane=tid&63, q=lane>>4, lr=lane&15;
  int wrow=(w>>1)*64, wcol=(w&1)*64;
  int srow = tid>>2, scol = (tid&3)*8;
  const u16* ga  = Ab + (long)(m0+srow)*lda + scol;
  const u16* ga2 = Ab + (long)(m0+64+srow)*lda + scol;
  const u16* gb  = Bb + (long)(n0+srow)*ldb + scol;
  const u16* gb2 = Bb + (long)(n0+64+srow)*ldb + scol;
  u16* la  = &As[srow*32 + scol];
  u16* la2 = &As[(64+srow)*32 + scol];
  u16* lb  = &Bs[srow*32 + scol];
  u16* lb2 = &Bs[(64+srow)*32 + scol];
  f4 acc[4][4] = {};
  for(int k0=0;k0<K;k0+=32){
    gload_lds(ga, la);  gload_lds(ga2, la2);
    gload_lds(gb, lb);  gload_lds(gb2, lb2);
    ga+=32; ga2+=32; gb+=32; gb2+=32;
    __syncthreads();
    bf8 af[4], bfr[4];
    #pragma unroll
    for(int r=0;r<4;r++) af[r]  = *(const bf8*)&As[(wrow + r*16 + lr)*32 + q*8];
    #pragma unroll
    for(int t=0;t<4;t++) bfr[t] = *(const bf8*)&Bs[(wcol + t*16 + lr)*32 + q*8];
    #pragma unroll
    for(int r=0;r<4;r++)
      #pragma unroll
      for(int t=0;t<4;t++)
        acc[r][t] = __builtin_amdgcn_mfma_f32_16x16x32_bf16(af[r], bfr[t], acc[r][t], 0,0,0);
    __syncthreads();
  }
  #pragma unroll
  for(int r=0;r<4;r++){
    #pragma unroll
    for(int t=0;t<4;t++){
      #pragma unroll
      for(int e=0;e<4;e++){
        int gm = m0 + wrow + r*16 + q*4 + e;
        int gn = n0 + wcol + t*16 + lr;
        float v = acc[r][t][e]*alpha;
        if(bias) v += bias[gn];
        if(relu) v = fmaxf(v,0.f);
        if(MODE==0) C[cb + (long)gm*ldc + gn] = v;
        else if(MODE==2) C16[cb + (long)gm*ldc + gn] = f2b(v);
        else { if(gm>=rowoff) C[cb + (long)(gm-rowoff)*ldc + gn] += v; }
      }
    }
  }
}

// ======== 64x64 NT bf16 GEMM, split-K capable ========
// MODE 0: fp32 store; MODE 2: bf16 store; MODE 3: fp32 atomicAdd
template<int MODE>
__global__ __launch_bounds__(256)
void k_g64(const u16* __restrict__ A, const u16* __restrict__ B,
           float* __restrict__ C, u16* __restrict__ C16,
           int K, int lda, int ldb, int ldc,
           long sAb, long sAh, long sBb, long sBh, long sCb, long sCh, int nh,
           float alpha, int nx, int ksplit)
{
  int z = blockIdx.z;
  const u16* Ab = A + (long)(z/nh)*sAb + (long)(z%nh)*sAh;
  const u16* Bb = B + (long)(z/nh)*sBb + (long)(z%nh)*sBh;
  long cb = (long)(z/nh)*sCb + (long)(z%nh)*sCh;
  int bx = blockIdx.x % nx, kc = blockIdx.x / nx;
  int m0 = blockIdx.y*64, n0 = bx*64;
  int klen = K/ksplit, kbeg = kc*klen;
  __shared__ u16 As[64*32];
  __shared__ u16 Bs[64*32];
  int tid=threadIdx.x, w=tid>>6, lane=tid&63, q=lane>>4, lr=lane&15;
  int srow = tid>>2, scol = (tid&3)*8;
  const u16* ga = Ab + (long)(m0+srow)*lda + kbeg + scol;
  const u16* gb = Bb + (long)(n0+srow)*ldb + kbeg + scol;
  u16* la = &As[srow*32 + scol];
  u16* lb = &Bs[srow*32 + scol];
  f4 acc[4] = {};
  for(int kk=0;kk<klen;kk+=32){
    gload_lds(ga, la); gload_lds(gb, lb);
    ga+=32; gb+=32;
    __syncthreads();
    bf8 af = *(const bf8*)&As[(w*16 + lr)*32 + q*8];
    #pragma unroll
    for(int t=0;t<4;t++){
      bf8 bfr = *(const bf8*)&Bs[(t*16 + lr)*32 + q*8];
      acc[t] = __builtin_amdgcn_mfma_f32_16x16x32_bf16(af, bfr, acc[t], 0,0,0);
    }
    __syncthreads();
  }
  #pragma unroll
  for(int t=0;t<4;t++){
    #pragma unroll
    for(int e=0;e<4;e++){
      int gm = m0 + w*16 + q*4 + e;
      int gn = n0 + t*16 + lr;
      float v = acc[t][e]*alpha;
      if(MODE==0) C[cb + (long)gm*ldc + gn] = v;
      else if(MODE==2) C16[cb + (long)gm*ldc + gn] = f2b(v);
      else atomicAdd(&C[cb + (long)gm*ldc + gn], v);
    }
  }
}

// ======== pinv GEMM on bf16 hi/lo pairs — pipelined ping-pong staging ========
__global__ __launch_bounds__(256)
void k_pg3(const u16* __restrict__ Ah, const u16* __restrict__ Al,
           const u16* __restrict__ Bh, const u16* __restrict__ Bl,
           u16* __restrict__ Oh, u16* __restrict__ Ol, float na, float nd,
           u16* __restrict__ TOh, u16* __restrict__ TOl, float ta, float td)
{
  long zo = (long)blockIdx.z*65536;
  int m0 = blockIdx.y*64, n0 = blockIdx.x*64;
  __shared__ u16 S[2][4][2048];
  int tid=threadIdx.x, w=tid>>6, lane=tid&63, q=lane>>4, lr=lane&15;
  int srow=tid>>2, scol=(tid&3)*8;
  long ao = zo + (long)(m0+srow)*256 + scol;
  long bo = zo + (long)(n0+srow)*256 + scol;
  int lo = srow*32 + scol;
  int aoff = (w*16+lr)*32 + q*8;
  f4 acc[4] = {};
  auto stage = [&](int r, int c){
    gload_lds(Ah+ao+c*32, &S[r][0][lo]);
    gload_lds(Al+ao+c*32, &S[r][1][lo]);
    gload_lds(Bh+bo+c*32, &S[r][2][lo]);
    gload_lds(Bl+bo+c*32, &S[r][3][lo]);
  };
  auto compute = [&](int r){
    bf8 ah = *(const bf8*)&S[r][0][aoff];
    bf8 al = *(const bf8*)&S[r][1][aoff];
    #pragma unroll
    for(int t=0;t<4;t++){
      int boff = (t*16+lr)*32 + q*8;
      bf8 bh = *(const bf8*)&S[r][2][boff];
      bf8 bl = *(const bf8*)&S[r][3][boff];
      acc[t] = __builtin_amdgcn_mfma_f32_16x16x32_bf16(ah, bh, acc[t], 0,0,0);
      acc[t] = __builtin_amdgcn_mfma_f32_16x16x32_bf16(ah, bl, acc[t], 0,0,0);
      acc[t] = __builtin_amdgcn_mfma_f32_16x16x32_bf16(al, bh, acc[t], 0,0,0);
    }
  };
  stage(0,0);
  __syncthreads();
  #pragma unroll
  for(int c=1;c<8;c++){
    stage(c&1, c);
    compute((c-1)&1);
    __syncthreads();
  }
  compute(1);
  #pragma unroll
  for(int t=0;t<4;t++){
    int gn = n0 + t*16 + lr;
    if(Oh){
      #pragma unroll
      for(int r=0;r<4;r++){
        int gm = m0 + w*16 + q*4 + r;
        float v = na*acc[t][r] + ((gm==gn)?nd:0.f);
        u16 h = f2b(v);
        long o = zo + (long)gm*256 + gn;
        Oh[o] = h; Ol[o] = f2b(v - b2f(h));
      }
    }
    if(TOh){
      us4 th, tl;
      #pragma unroll
      for(int r=0;r<4;r++){
        int gm = m0 + w*16 + q*4 + r;
        float v = ta*acc[t][r] + ((gm==gn)?td:0.f);
        u16 h = f2b(v);
        th[r] = h; tl[r] = f2b(v - b2f(h));
      }
      long o = zo + (long)gn*256 + (m0 + w*16 + q*4);
      *(us4*)&TOh[o] = th; *(us4*)&TOl[o] = tl;
    }
  }
}

// ======== fused attn1: S=SCALE*q@kl^T; P=softmax(S); Qc=P@zav ========
// grid (NP/64, 16), block 256. z = b*8+h.
__global__ __launch_bounds__(256)
void k_att1(const u16* __restrict__ qkv16, const u16* __restrict__ kl,
            const u16* __restrict__ zavT, float* __restrict__ Qc)
{
  int z = blockIdx.y, b = z>>3, h = z&7;
  int m0 = blockIdx.x*64;
  __shared__ u16 SQ[64*64];      // q tile [m][k]
  __shared__ u16 SKL[256*64];    // kl [l][k]; later reused as PS[64][256]
  __shared__ u16 SZV[64*256];    // zavT [d][l]
  int tid=threadIdx.x, w=tid>>6, lane=tid&63, q=lane>>4, lr=lane&15;
  // stage q (2 issues), kl (8), zav (8)
  {
    const u16* qb = qkv16 + (long)b*NP*1536 + h*64;
    #pragma unroll
    for(int p=0;p<2;p++){
      int idx = tid + p*256; int row = idx>>3, c8 = (idx&7)*8;
      gload_lds(qb + (long)(m0+row)*1536 + c8, &SQ[row*64 + c8]);
    }
    const u16* kb = kl + (long)z*16384;
    #pragma unroll
    for(int p=0;p<8;p++){
      int idx = tid + p*256; int row = idx>>3, c8 = (idx&7)*8;
      gload_lds(kb + row*64 + c8, &SKL[row*64 + c8]);
    }
    const u16* zb = zavT + (long)z*16384;
    #pragma unroll
    for(int p=0;p<8;p++){
      int idx = tid + p*256; int row = idx>>5, c8 = (idx&31)*8;
      gload_lds(zb + row*256 + c8, &SZV[row*256 + c8]);
    }
  }
  __syncthreads();
  // S = q @ kl^T : wave w -> m rows w*16..w*16+15; acc[16] n-tiles
  f4 acc[16] = {};
  {
    bf8 af0 = *(const bf8*)&SQ[(w*16+lr)*64 + q*8];
    bf8 af1 = *(const bf8*)&SQ[(w*16+lr)*64 + 32 + q*8];
    #pragma unroll
    for(int t=0;t<16;t++){
      bf8 b0 = *(const bf8*)&SKL[(t*16+lr)*64 + q*8];
      bf8 b1 = *(const bf8*)&SKL[(t*16+lr)*64 + 32 + q*8];
      acc[t] = __builtin_amdgcn_mfma_f32_16x16x32_bf16(af0, b0, acc[t], 0,0,0);
      acc[t] = __builtin_amdgcn_mfma_f32_16x16x32_bf16(af1, b1, acc[t], 0,0,0);
    }
  }
  // softmax over the 256 cols of each row (C layout: col=lr, row=q*4+e)
  float mx[4] = {-1e30f,-1e30f,-1e30f,-1e30f};
  #pragma unroll
  for(int t=0;t<16;t++)
    #pragma unroll
    for(int e=0;e<4;e++) mx[e] = fmaxf(mx[e], acc[t][e]*SCALE);
  #pragma unroll
  for(int s=1;s<16;s<<=1)
    #pragma unroll
    for(int e=0;e<4;e++) mx[e] = fmaxf(mx[e], __shfl_xor(mx[e], s));
  float sm[4] = {0.f,0.f,0.f,0.f};
  #pragma unroll
  for(int t=0;t<16;t++)
    #pragma unroll
    for(int e=0;e<4;e++){ float p = expf(acc[t][e]*SCALE - mx[e]); acc[t][e]=p; sm[e]+=p; }
  #pragma unroll
  for(int s=1;s<16;s<<=1)
    #pragma unroll
    for(int e=0;e<4;e++) sm[e] += __shfl_xor(sm[e], s);
  float inv[4];
  #pragma unroll
  for(int e=0;e<4;e++) inv[e] = 1.f/sm[e];
  __syncthreads();                 // all waves done reading SKL
  // P -> LDS (A-operand layout), reuse SKL as PS[64][256]
  u16* PS = SKL;
  #pragma unroll
  for(int t=0;t<16;t++)
    #pragma unroll
    for(int e=0;e<4;e++)
      PS[(w*16 + q*4 + e)*256 + t*16 + lr] = f2b(acc[t][e]*inv[e]);
  __syncthreads();
  // O = P @ zav : A = PS [m][l], B = SZV [d][l]; acc2[4] n-tiles of d
  f4 acc2[4] = {};
  #pragma unroll
  for(int ks=0;ks<8;ks++){
    bf8 af = *(const bf8*)&PS[(w*16+lr)*256 + ks*32 + q*8];
    #pragma unroll
    for(int t=0;t<4;t++){
      bf8 bf_ = *(const bf8*)&SZV[(t*16+lr)*256 + ks*32 + q*8];
      acc2[t] = __builtin_amdgcn_mfma_f32_16x16x32_bf16(af, bf_, acc2[t], 0,0,0);
    }
  }
  #pragma unroll
  for(int t=0;t<4;t++)
    #pragma unroll
    for(int r=0;r<4;r++){
      int gm = m0 + w*16 + q*4 + r;
      int gd = t*16 + lr;
      Qc[((long)b*NP + gm)*512 + h*64 + gd] = acc2[t][r];
    }
}

// ======== softmax: wave per row, 256 cols, fp32 ========
__global__ __launch_bounds__(256)
void k_smw32(float* __restrict__ X){
  long row = (long)blockIdx.x*4 + (threadIdx.x>>6);
  int lane = threadIdx.x & 63;
  float* p = X + row*256;
  float4 v = *(float4*)&p[lane*4];
  float m = fmaxf(fmaxf(v.x,v.y),fmaxf(v.z,v.w));
  for(int s=32;s;s>>=1) m = fmaxf(m, __shfl_xor(m, s));
  float e0=expf(v.x-m), e1=expf(v.y-m), e2=expf(v.z-m), e3=expf(v.w-m);
  float sum = e0+e1+e2+e3;
  for(int s=32;s;s>>=1) sum += __shfl_xor(sum, s);
  float inv = 1.f/sum;
  float4 o = {e0*inv, e1*inv, e2*inv, e3*inv};
  *(float4*)&p[lane*4] = o;
}

// ======== softmax: block per row, 4352 cols, register-resident bf16 ========
__global__ __launch_bounds__(256)
void k_smb16(u16* __restrict__ X){
  u16* p = X + (long)blockIdx.x*4352;
  int tid=threadIdx.x, lane=tid&63, w=tid>>6;
  __shared__ float xw[4], sw[4];
  float e[17];
  float m = -1e30f;
  #pragma unroll
  for(int i=0;i<17;i++){ e[i] = b2f(p[tid + i*256]); m = fmaxf(m, e[i]); }
  for(int s=32;s;s>>=1) m = fmaxf(m, __shfl_xor(m, s));
  if(lane==0) xw[w] = m;
  __syncthreads();
  m = fmaxf(fmaxf(xw[0],xw[1]), fmaxf(xw[2],xw[3]));
  float sum = 0.f;
  #pragma unroll
  for(int i=0;i<17;i++){ e[i] = expf(e[i]-m); sum += e[i]; }
  for(int s=32;s;s>>=1) sum += __shfl_xor(sum, s);
  if(lane==0) sw[w] = sum;
  __syncthreads();
  sum = sw[0]+sw[1]+sw[2]+sw[3];
  float inv = 1.f/sum;
  #pragma unroll
  for(int i=0;i<17;i++) p[tid + i*256] = f2b(e[i]*inv);
}

// weight transpose+convert: in fp32 [K][N] -> out bf16 [N][K]
__global__ void k_wT(const float* __restrict__ in, u16* __restrict__ out, int K, int N){
  int n0=blockIdx.x*32, k0=blockIdx.y*32, tid=threadIdx.x;
  __shared__ float T[32][33];
  int lr=tid&31, lc=tid>>5;
  #pragma unroll
  for(int p=0;p<4;p++) T[lc+8*p][lr] = in[(long)(k0+lc+8*p)*N + n0+lr];
  __syncthreads();
  #pragma unroll
  for(int p=0;p<4;p++) out[(long)(n0+lc+8*p)*K + k0+lr] = f2b(T[lr][lc+8*p]);
}

// v^T: qkvb16 v-section [NP][64] per (b,h) -> vT [b][h][64][NP]
__global__ __launch_bounds__(256)
void k_vT(const u16* __restrict__ qkv16, u16* __restrict__ vT){
  int t0=blockIdx.x*64, h=blockIdx.y, b=blockIdx.z, tid=threadIdx.x;
  __shared__ u16 T[64][72];
  const u16* src = qkv16 + (long)b*NP*1536 + 1024 + h*64;
  for(int s=0;s<2;s++){
    int idx=tid+s*256; int row=idx>>3, c8=(idx&7)*8;
    *(us8*)&T[row][c8] = *(const us8*)&src[(long)(t0+row)*1536 + c8];
  }
  __syncthreads();
  u16* dst = vT + ((long)(b*8+h)*64)*NP;
  int d = tid>>2, j0=(tid&3)*16;
  us8 v0,v1;
  #pragma unroll
  for(int jj=0;jj<8;jj++){ v0[jj]=T[j0+jj][d]; v1[jj]=T[j0+8+jj][d]; }
  *(us8*)&dst[(long)d*NP + t0 + j0]     = v0;
  *(us8*)&dst[(long)d*NP + t0 + j0 + 8] = v1;
}

__global__ void k_cvt16(const float* __restrict__ in, u16* __restrict__ out, long n){
  long i = (long)blockIdx.x*256 + threadIdx.x;
  if(i<n) out[i] = f2b(in[i]);
}

__global__ void k_zero(float* __restrict__ p, long n){
  long i = (long)blockIdx.x*256 + threadIdx.x;
  if(i<n) p[i] = 0.f;
}

__global__ void k_cls(const float* __restrict__ cls, float* __restrict__ seq){
  int b = blockIdx.x;
  seq[(long)b*NTOK*EMB + threadIdx.x] = cls[threadIdx.x];
}

// LayerNorm of seq into xpb bf16 with 255 zero rows at front
__global__ void k_ln_pad(const float* __restrict__ seq, u16* __restrict__ xp,
                         const float* __restrict__ g, const float* __restrict__ bb){
  int b = blockIdx.y, i = blockIdx.x, tid = threadIdx.x;
  u16* out = xp + ((long)b*NP + i)*EMB;
  if(i < PADF){ out[tid]=0; out[tid+256]=0; return; }
  const float* x = seq + ((long)b*NTOK + (i-PADF))*EMB;
  float v0 = x[tid], v1 = x[tid+256];
  __shared__ float red[256];
  red[tid]=v0+v1; __syncthreads();
  for(int s=128;s>0;s>>=1){ if(tid<s) red[tid]+=red[tid+s]; __syncthreads(); }
  float mu = red[0]*(1.0f/512.0f); __syncthreads();
  float d0=v0-mu, d1=v1-mu;
  red[tid]=d0*d0+d1*d1; __syncthreads();
  for(int s=128;s>0;s>>=1){ if(tid<s) red[tid]+=red[tid+s]; __syncthreads(); }
  float rstd = rsqrtf(red[0]*(1.0f/512.0f) + 1e-5f);
  out[tid]     = f2b(d0*rstd*g[tid]     + bb[tid]);
  out[tid+256] = f2b(d1*rstd*g[tid+256] + bb[tid+256]);
}

__global__ void k_landmarks(const u16* __restrict__ qkv, u16* __restrict__ q_l, u16* __restrict__ k_l){
  int j = blockIdx.x, h = blockIdx.y, b = blockIdx.z, d = threadIdx.x;
  const u16* base = qkv + (long)b*NP*1536 + h*64 + d;
  float sq=0.f, sk=0.f;
  for(int l=0;l<17;l++){
    long row = (long)(j*17+l)*1536;
    sq += b2f(base[row]);
    sk += b2f(base[row+512]);
  }
  long o = (((long)b*HEADS + h)*LM + j)*DH + d;
  q_l[o] = f2b(sq * (SCALE/17.0f));
  k_l[o] = f2b(sk * (1.0f/17.0f));
}

__global__ void k_pinv_norm(const float* __restrict__ A2, float* __restrict__ rmax, float* __restrict__ cmax){
  int z = blockIdx.x, tid = threadIdx.x;
  const float* X = A2 + (long)z*65536;
  float rs=0.f, cs=0.f;
  for(int j=0;j<256;j++){ rs += fabsf(X[tid*256+j]); cs += fabsf(X[j*256+tid]); }
  __shared__ float r1[256], r2[256];
  r1[tid]=rs; r2[tid]=cs; __syncthreads();
  for(int s=128;s>0;s>>=1){ if(tid<s){ r1[tid]=fmaxf(r1[tid],r1[tid+s]); r2[tid]=fmaxf(r2[tid],r2[tid+s]); } __syncthreads(); }
  if(tid==0){ rmax[z]=r1[0]; cmax[z]=r2[0]; }
}

__global__ void k_pair_init(const float* __restrict__ att2,
    const float* __restrict__ rmax, const float* __restrict__ cmax,
    u16* __restrict__ Xh, u16* __restrict__ Xl,
    u16* __restrict__ Zh, u16* __restrict__ Zl,
    u16* __restrict__ Zth, u16* __restrict__ Ztl)
{
  long zo = (long)blockIdx.z*65536;
  int i0 = blockIdx.y*64, j0 = blockIdx.x*64;
  float rm=0.f, cm=0.f;
  for(int t=0;t<16;t++){ rm=fmaxf(rm,rmax[t]); cm=fmaxf(cm,cmax[t]); }
  float inv = 1.0f/(rm*cm);
  __shared__ float T[64][68];
  int tid = threadIdx.x;
  int li = tid>>2, jc = (tid&3)*16;
  #pragma unroll
  for(int u=0;u<4;u++){
    float4 v = *(const float4*)&att2[zo + (long)(i0+li)*256 + j0 + jc + u*4];
    T[li][jc+u*4]=v.x; T[li][jc+u*4+1]=v.y; T[li][jc+u*4+2]=v.z; T[li][jc+u*4+3]=v.w;
    long o = zo + (long)(i0+li)*256 + j0 + jc + u*4;
    float vv[4] = {v.x,v.y,v.z,v.w};
    us4 xh, xl, zth, ztl;
    #pragma unroll
    for(int c=0;c<4;c++){
      u16 h = f2b(vv[c]); xh[c]=h; xl[c]=f2b(vv[c]-b2f(h));
      float zt = vv[c]*inv;
      u16 h2 = f2b(zt); zth[c]=h2; ztl[c]=f2b(zt-b2f(h2));
    }
    *(us4*)&Xh[o]=xh; *(us4*)&Xl[o]=xl; *(us4*)&Zth[o]=zth; *(us4*)&Ztl[o]=ztl;
  }
  __syncthreads();
  int lj = tid>>2, ic = (tid&3)*16;
  #pragma unroll
  for(int r=0;r<16;r++){
    float x = T[ic+r][lj]*inv;
    u16 h = f2b(x);
    long o = zo + (long)(j0+lj)*256 + i0 + ic + r;
    Zh[o]=h; Zl[o]=f2b(x-b2f(h));
  }
}

// res conv + fused bf16 convert: Qc16 = bf16(Qc + dwconv(v))
__global__ __launch_bounds__(256)
void k_rconv(const u16* __restrict__ qkv16, const float* __restrict__ resk,
             const float* __restrict__ Qin, u16* __restrict__ Qo16){
  int t0 = blockIdx.x*64, h = blockIdx.y, b = blockIdx.z;
  __shared__ float V[96*64];
  const u16* vb = qkv16 + (long)b*NP*1536 + 1024 + h*64;
  int tid = threadIdx.x;
  #pragma unroll
  for(int s=0;s<3;s++){
    int idx = tid + s*256;
    int row = idx>>3, c8 = (idx&7)*8;
    int p = t0 - 16 + row;
    if(p>=0 && p<NP){
      us8 v = *(const us8*)&vb[(long)p*1536 + c8];
      #pragma unroll
      for(int jj=0;jj<8;jj++) V[row*64+c8+jj] = b2f(v[jj]);
    } else {
      #pragma unroll
      for(int jj=0;jj<8;jj++) V[row*64+c8+jj] = 0.f;
    }
  }
  __syncthreads();
  int d = tid&63, lt = (tid>>6)*16;
  float acc[16] = {};
  #pragma unroll
  for(int s=0;s<48;s++){
    float val = V[(lt+s)*64 + d];
    #pragma unroll
    for(int j=0;j<16;j++){
      int tap = s - j;
      if(tap>=0 && tap<33) acc[j] += resk[h*33+tap]*val;
    }
  }
  #pragma unroll
  for(int j=0;j<16;j++){
    long idx = ((long)b*NP + t0 + lt + j)*EMB + h*64 + d;
    Qo16[idx] = f2b(Qin[idx] + acc[j]);
  }
}

// PPEG: 64-ch groups, 4 rows x 64 ch per block, x-split 2; grid (32, 8, 2)
__global__ __launch_bounds__(256)
void k_ppeg(const float* __restrict__ seq, float* __restrict__ out,
    const float* __restrict__ w7,const float* __restrict__ b7,
    const float* __restrict__ w5,const float* __restrict__ b5,
    const float* __restrict__ w3,const float* __restrict__ b3){
  int b = blockIdx.z, cg = blockIdx.y;
  int rp = blockIdx.x>>1, xs = blockIdx.x&1;
  int ch0 = cg*64;
  __shared__ float s7[64*49], s5[64*25], s3[64*9], sbias[64];
  int tid = threadIdx.x;
  for(int i=tid;i<64*49;i+=256) s7[i] = w7[ch0*49+i];
  for(int i=tid;i<64*25;i+=256) s5[i] = w5[ch0*25+i];
  for(int i=tid;i<64*9;i+=256)  s3[i] = w3[ch0*9+i];
  if(tid<64) sbias[tid] = b7[ch0+tid]+b5[ch0+tid]+b3[ch0+tid];
  if(cg==0 && blockIdx.x==0){
    out[(long)b*NTOK*EMB + tid]       = seq[(long)b*NTOK*EMB + tid];
    out[(long)b*NTOK*EMB + 256 + tid] = seq[(long)b*NTOK*EMB + 256 + tid];
  }
  __syncthreads();
  int c = tid & 63;
  int y = rp*4 + (tid>>6);
  const float* sbase = seq + (long)b*NTOK*EMB + EMB + (ch0 + c);
  float* obase = out + (long)b*NTOK*EMB + EMB + (ch0 + c);
  const float* W7 = &s7[c*49];
  const float* W5 = &s5[c*25];
  const float* W3 = &s3[c*9];
  float bsum = sbias[c];
  for(int xc=0;xc<4;xc++){
    int xb = xs*32 + xc*8;
    float acc[8];
    #pragma unroll
    for(int j=0;j<8;j++) acc[j] = sbase[(long)(y*64+xb+j)*EMB] + bsum;
    #pragma unroll
    for(int dy=-3;dy<=3;dy++){
      int yy = y+dy;
      if(yy<0||yy>=64) continue;
      float v[14];
      #pragma unroll
      for(int u=0;u<14;u++){
        int xx = xb + u - 3;
        v[u] = (xx>=0 && xx<64) ? sbase[(long)(yy*64+xx)*EMB] : 0.f;
      }
      #pragma unroll
      for(int dx=-3;dx<=3;dx++){
        float wsum = W7[(dy+3)*7+(dx+3)];
        if(dy>=-2&&dy<=2&&dx>=-2&&dx<=2) wsum += W5[(dy+2)*5+(dx+2)];
        if(dy>=-1&&dy<=1&&dx>=-1&&dx<=1) wsum += W3[(dy+1)*3+(dx+1)];
        #pragma unroll
        for(int j=0;j<8;j++) acc[j] += v[j+dx+3]*wsum;
      }
    }
    #pragma unroll
    for(int j=0;j<8;j++) obase[(long)(y*64+xb+j)*EMB] = acc[j];
  }
}

__global__ void k_final_ln(const float* __restrict__ seq, const float* __restrict__ g,
                           const float* __restrict__ bb, float* __restrict__ out){
  int b = blockIdx.x, tid = threadIdx.x;
  const float* x = seq + (long)b*NTOK*EMB;
  float v0 = x[tid], v1 = x[tid+256];
  __shared__ float red[256];
  red[tid]=v0+v1; __syncthreads();
  for(int s=128;s>0;s>>=1){ if(tid<s) red[tid]+=red[tid+s]; __syncthreads(); }
  float mu = red[0]*(1.0f/512.0f); __syncthreads();
  float d0=v0-mu, d1=v1-mu;
  red[tid]=d0*d0+d1*d1; __syncthreads();
  for(int s=128;s>0;s>>=1){ if(tid<s) red[tid]+=red[tid+s]; __syncthreads(); }
  float rstd = rsqrtf(red[0]*(1.0f/512.0f) + 1e-5f);
  out[b*512+tid]     = d0*rstd*g[tid]     + bb[tid];
  out[b*512+tid+256] = d1*rstd*g[tid+256] + bb[tid+256];
}

// ---------------- host ----------------
extern "C" void kernel_launch(void* const* d_in, const int* in_sizes, int n_in,
                              void* d_out, int out_size, void* d_ws, size_t ws_size,
                              hipStream_t stream) {
  const float* in[24];
  for(int i=0;i<24;i++) in[i] = (const float*)d_in[i];

  float* W = (float*)d_ws;
  size_t off = 0;
  float* seqA = W+off; off += 4195328;        // 2*4097*512
  float* seqB = W+off; off += 4195328;
  float* att2 = W+off; off += 1048576;        // 16*65536
  float* Qc   = W+off; off += 4456448;        // 2*4352*512
  float* avbT = W+off; off += 262144;         // 16*64*256
  u16* xpb    = (u16*)(W+off); off += 2228224;  // 2*4352*512 u16
  u16* qkvb16 = (u16*)(W+off); off += 6684672;  // 2*4352*1536 u16
  u16* vT16   = (u16*)(W+off); off += 2228224;
  u16* q_l16  = (u16*)(W+off); off += 131072;   // 16*256*64 u16
  u16* k_l16  = (u16*)(W+off); off += 131072;
  u16* sc16   = (u16*)(W+off); off += 8912896;  // 16*256*4352 u16
  u16* avbT16 = (u16*)(W+off); off += 131072;
  u16* zavT16 = (u16*)(W+off); off += 131072;
  u16* Qc16   = (u16*)(W+off); off += 2228224;
  u16* qkvwT1 = (u16*)(W+off); off += 393216;   // 1536*512 u16
  u16* qkvwT2 = (u16*)(W+off); off += 393216;
  u16* outwT1 = (u16*)(W+off); off += 131072;   // 512*512 u16
  u16* outwT2 = (u16*)(W+off); off += 131072;
  u16* pairs  = (u16*)(W+off); off += 9437184;  // 18*16*65536 u16
  float* rmax = W+off; off += 16;
  float* cmax = W+off; off += 16;
  if (ws_size < off*sizeof(float)) return;

  // h16 + wfc1T aliased inside sc16 (sc16 first written later, in attention())
  u16* h16   = sc16;                  // 8388608 u16
  u16* wfc1T = sc16 + 8388608;        // 524288 u16

  const long PB = 1048576;  // 16*65536
  u16 *Xh=pairs, *Xl=pairs+PB;
  u16 *Z0h=pairs+2*PB, *Z0l=pairs+3*PB, *Z0th=pairs+4*PB, *Z0tl=pairs+5*PB;
  u16 *Z1h=pairs+6*PB, *Z1l=pairs+7*PB, *Z1th=pairs+8*PB, *Z1tl=pairs+9*PB;
  u16 *Ph=pairs+10*PB, *Pl=pairs+11*PB;
  u16 *Tth=pairs+12*PB, *Ttl=pairs+13*PB;
  u16 *Uth=pairs+14*PB, *Utl=pairs+15*PB;
  u16 *Vth=pairs+16*PB, *Vtl=pairs+17*PB;

  // weight conversions/transposes
  k_cvt16<<<32768,256,0,stream>>>(in[0], h16, 8388608L);
  k_wT<<<dim3(16,32),256,0,stream>>>(in[1],  wfc1T, 1024, 512);
  k_wT<<<dim3(48,16),256,0,stream>>>(in[6],  qkvwT1, 512, 1536);
  k_wT<<<dim3(48,16),256,0,stream>>>(in[18], qkvwT2, 512, 1536);
  k_wT<<<dim3(16,16),256,0,stream>>>(in[7],  outwT1, 512, 512);
  k_wT<<<dim3(16,16),256,0,stream>>>(in[19], outwT2, 512, 512);

  // fc1 + cls
  k_g128<0><<<dim3(4,32,2),256,0,stream>>>(h16, wfc1T, seqA+EMB, nullptr,
      1024, 1024,1024,512, 4194304L,0, 0,0, (long)NTOK*EMB,0, 1, 1.0f, in[2], 1, 0);
  k_cls<<<2,512,0,stream>>>(in[3], seqA);

  auto attention = [&](float* seq, const float* lng,const float* lnb,
                       const u16* qkvwT, const u16* outwT, const float* outb, const float* resk){
    k_ln_pad<<<dim3(NP,2),256,0,stream>>>(seq, xpb, lng, lnb);
    k_g128<2><<<dim3(12,34,2),256,0,stream>>>(xpb, qkvwT, nullptr, qkvb16,
        512, 512,512,1536, (long)NP*512,0, 0,0, (long)NP*1536,0, 1, 1.0f, nullptr, 0, 0);
    k_landmarks<<<dim3(LM,HEADS,2),64,0,stream>>>(qkvb16, q_l16, k_l16);
    k_vT<<<dim3(68,8,2),256,0,stream>>>(qkvb16, vT16);
    // attn2 = softmax(q_l @ k_l^T)  (fp32 scores for pinv)
    k_g128<0><<<dim3(2,2,16),256,0,stream>>>(q_l16, k_l16, att2, nullptr,
        64, 64,64,256, 0,16384, 0,16384, 0,65536, 16, 1.0f, nullptr, 0, 0);
    k_smw32<<<1024,256,0,stream>>>(att2);
    // pinv on bf16 pairs
    k_pinv_norm<<<16,256,0,stream>>>(att2, rmax, cmax);
    k_pair_init<<<dim3(4,4,16),256,0,stream>>>(att2, rmax, cmax, Xh,Xl, Z0h,Z0l, Z0th,Z0tl);
    dim3 pgrid(4,4,16);
    for(int it=0; it<6; it++){
      u16 *Zh_=(it&1)?Z1h:Z0h, *Zl_=(it&1)?Z1l:Z0l, *Zth_=(it&1)?Z1th:Z0th, *Ztl_=(it&1)?Z1tl:Z0tl;
      u16 *Nh_=(it&1)?Z0h:Z1h, *Nl_=(it&1)?Z0l:Z1l, *Nth_=(it&1)?Z0th:Z1th, *Ntl_=(it&1)?Z0tl:Z1tl;
      k_pg3<<<pgrid,256,0,stream>>>(Xh,Xl, Zth_,Ztl_, Ph,Pl,1.0f,0.f, Tth,Ttl,-1.0f,7.f);
      k_pg3<<<pgrid,256,0,stream>>>(Ph,Pl, Tth,Ttl, nullptr,nullptr,0.f,0.f, Uth,Utl,-1.0f,15.f);
      k_pg3<<<pgrid,256,0,stream>>>(Ph,Pl, Uth,Utl, nullptr,nullptr,0.f,0.f, Vth,Vtl,-1.0f,13.f);
      if(it<5) k_pg3<<<pgrid,256,0,stream>>>(Zh_,Zl_, Vth,Vtl, Nh_,Nl_,0.25f,0.f, Nth_,Ntl_,0.25f,0.f);
      else     k_pg3<<<pgrid,256,0,stream>>>(Zh_,Zl_, Vth,Vtl, Nh_,Nl_,0.25f,0.f, nullptr,nullptr,0.f,0.f);
    }
    // attn3 scores = q_l @ k^T -> sc16 (bf16)
    k_g128<2><<<dim3(34,2,16),256,0,stream>>>(q_l16, qkvb16+512, nullptr, sc16,
        64, 64,1536,4352, 131072L,16384, (long)NP*1536,64, 8L*LM*NP,(long)LM*NP, 8, 1.0f, nullptr, 0, 0);
    k_smb16<<<4096,256,0,stream>>>(sc16);
    // avbT = v^T @ attn3_sm^T (split-K atomic)
    k_zero<<<1024,256,0,stream>>>(avbT, 262144L);
    k_g64<3><<<dim3(4*17,1,16),256,0,stream>>>(vT16, sc16, avbT, nullptr,
        4352, 4352,4352,256, 2228224L,278528L, 8L*LM*NP,(long)LM*NP, 131072L,16384L, 8, 1.0f, 4, 17);
    k_cvt16<<<1024,256,0,stream>>>(avbT, avbT16, 262144L);
    // zavT = avbT @ Z^T  -> bf16
    k_g64<2><<<dim3(4,1,16),256,0,stream>>>(avbT16, Z0h, nullptr, zavT16,
        256, 256,256,256, 0,16384L, 0,65536L, 0,16384L, 16, 1.0f, 4, 1);
    // fused attn1: scores + softmax + @zav -> Qc
    k_att1<<<dim3(68,16),256,0,stream>>>(qkvb16, k_l16, zavT16, Qc);
    // res conv fused with bf16 convert
    k_rconv<<<dim3(68,8,2),256,0,stream>>>(qkvb16, resk, Qc, Qc16);
    // out proj + residual add into seq
    k_g128<3><<<dim3(4,34,2),256,0,stream>>>(Qc16, outwT, seq, nullptr,
        512, 512,512,512, (long)NP*512,0, 0,0, (long)NTOK*EMB,0, 1, 1.0f, outb, 0, PADF);
  };

  attention(seqA, in[4], in[5], qkvwT1, outwT1, in[8], in[9]);
  k_ppeg<<<dim3(32,8,2),256,0,stream>>>(seqA, seqB, in[10],in[11],in[12],in[13],in[14],in[15]);
  attention(seqB, in[16], in[17], qkvwT2, outwT2, in[20], in[21]);
  k_final_ln<<<2,256,0,stream>>>(seqB, in[22], in[23], (float*)d_out);
}

// Round 12
// 1098.449 us; speedup vs baseline: 1.1422x; 1.0037x over previous
//
#include <hip/hip_runtime.h>
#include <hip/hip_bf16.h>

#define HEADS 8
#define DH 64
#define EMB 512
#define NP 4352
#define NTOK 4097
#define PADF 255
#define LM 256
#define SCALE 0.125f

typedef __attribute__((ext_vector_type(8))) short bf8;
typedef __attribute__((ext_vector_type(4))) float f4;
typedef __attribute__((ext_vector_type(8))) unsigned short us8;
typedef __attribute__((ext_vector_type(4))) unsigned short us4;
typedef unsigned short u16;

__device__ __forceinline__ u16 f2b(float f){
  union { float f; unsigned u; } x; x.f = f;
  unsigned r = x.u + 0x7fffu + ((x.u>>16)&1u);
  return (u16)(r>>16);
}
__device__ __forceinline__ float b2f(u16 h){
  union { unsigned u; float f; } x; x.u = ((unsigned)h)<<16;
  return x.f;
}

__device__ __forceinline__ void gload_lds(const u16* g, u16* l){
  __builtin_amdgcn_global_load_lds((const __attribute__((address_space(1))) void*)g,
                                   (__attribute__((address_space(3))) void*)l, 16, 0, 0);
}

// ======== 128x128 NT bf16 GEMM, BK=32, ping-pong pipelined staging ========
// MODE 0: fp32 store; MODE 2: bf16 store; MODE 3: fp32 C[gm-rowoff] += v;
// MODE 4: fp32 atomicAdd to C[gm-rowoff] (split-K safe; bias only on kc==0)
template<int MODE>
__global__ __launch_bounds__(256)
void k_g128(const u16* __restrict__ A, const u16* __restrict__ B,
            float* __restrict__ C, u16* __restrict__ C16,
            int K, int lda, int ldb, int ldc,
            long sAb, long sAh, long sBb, long sBh, long sCb, long sCh, int nh,
            float alpha, const float* __restrict__ bias, int relu, int rowoff,
            int nx, int ksplit)
{
  int z = blockIdx.z;
  const u16* Ab = A + (long)(z/nh)*sAb + (long)(z%nh)*sAh;
  const u16* Bb = B + (long)(z/nh)*sBb + (long)(z%nh)*sBh;
  long cb = (long)(z/nh)*sCb + (long)(z%nh)*sCh;
  int bx = blockIdx.x % nx, kc = blockIdx.x / nx;
  int m0 = blockIdx.y*128, n0 = bx*128;
  int klen = K/ksplit, kbeg = kc*klen, nch = klen/32;
  __shared__ u16 As[2][4096];
  __shared__ u16 Bs[2][4096];
  int tid=threadIdx.x, w=tid>>6, lane=tid&63, q=lane>>4, lr=lane&15;
  int wrow=(w>>1)*64, wcol=(w&1)*64;
  int srow = tid>>2, scol = (tid&3)*8;
  const u16* ga  = Ab + (long)(m0+srow)*lda + kbeg + scol;
  const u16* ga2 = Ab + (long)(m0+64+srow)*lda + kbeg + scol;
  const u16* gb  = Bb + (long)(n0+srow)*ldb + kbeg + scol;
  const u16* gb2 = Bb + (long)(n0+64+srow)*ldb + kbeg + scol;
  int lo = srow*32 + scol;
  f4 acc[4][4] = {};
  auto stage = [&](int r, int c){
    gload_lds(ga  + c*32, &As[r][lo]);
    gload_lds(ga2 + c*32, &As[r][2048+lo]);
    gload_lds(gb  + c*32, &Bs[r][lo]);
    gload_lds(gb2 + c*32, &Bs[r][2048+lo]);
  };
  auto compute = [&](int r){
    bf8 af[4], bfr[4];
    #pragma unroll
    for(int rr=0;rr<4;rr++) af[rr]  = *(const bf8*)&As[r][(wrow + rr*16 + lr)*32 + q*8];
    #pragma unroll
    for(int t=0;t<4;t++) bfr[t] = *(const bf8*)&Bs[r][(wcol + t*16 + lr)*32 + q*8];
    #pragma unroll
    for(int rr=0;rr<4;rr++)
      #pragma unroll
      for(int t=0;t<4;t++)
        acc[rr][t] = __builtin_amdgcn_mfma_f32_16x16x32_bf16(af[rr], bfr[t], acc[rr][t], 0,0,0);
  };
  stage(0,0);
  __syncthreads();
  for(int c=1;c<nch;c++){
    stage(c&1, c);
    compute((c-1)&1);
    __syncthreads();
  }
  compute((nch-1)&1);
  #pragma unroll
  for(int r=0;r<4;r++){
    #pragma unroll
    for(int t=0;t<4;t++){
      #pragma unroll
      for(int e=0;e<4;e++){
        int gm = m0 + wrow + r*16 + q*4 + e;
        int gn = n0 + wcol + t*16 + lr;
        float v = acc[r][t][e]*alpha;
        if(MODE==4){
          if(bias && kc==0) v += bias[gn];
          if(gm>=rowoff) atomicAdd(&C[cb + (long)(gm-rowoff)*ldc + gn], v);
        } else {
          if(bias) v += bias[gn];
          if(relu) v = fmaxf(v,0.f);
          if(MODE==0) C[cb + (long)gm*ldc + gn] = v;
          else if(MODE==2) C16[cb + (long)gm*ldc + gn] = f2b(v);
          else { if(gm>=rowoff) C[cb + (long)(gm-rowoff)*ldc + gn] += v; }
        }
      }
    }
  }
}

// ======== 64x64 NT bf16 GEMM, split-K capable, ping-pong pipelined ========
// MODE 0: fp32 store; MODE 2: bf16 store; MODE 3: fp32 atomicAdd
template<int MODE>
__global__ __launch_bounds__(256)
void k_g64(const u16* __restrict__ A, const u16* __restrict__ B,
           float* __restrict__ C, u16* __restrict__ C16,
           int K, int lda, int ldb, int ldc,
           long sAb, long sAh, long sBb, long sBh, long sCb, long sCh, int nh,
           float alpha, int nx, int ksplit)
{
  int z = blockIdx.z;
  const u16* Ab = A + (long)(z/nh)*sAb + (long)(z%nh)*sAh;
  const u16* Bb = B + (long)(z/nh)*sBb + (long)(z%nh)*sBh;
  long cb = (long)(z/nh)*sCb + (long)(z%nh)*sCh;
  int bx = blockIdx.x % nx, kc = blockIdx.x / nx;
  int m0 = blockIdx.y*64, n0 = bx*64;
  int klen = K/ksplit, kbeg = kc*klen, nch = klen/32;
  __shared__ u16 As[2][2048];
  __shared__ u16 Bs[2][2048];
  int tid=threadIdx.x, w=tid>>6, lane=tid&63, q=lane>>4, lr=lane&15;
  int srow = tid>>2, scol = (tid&3)*8;
  const u16* ga = Ab + (long)(m0+srow)*lda + kbeg + scol;
  const u16* gb = Bb + (long)(n0+srow)*ldb + kbeg + scol;
  int lo = srow*32 + scol;
  f4 acc[4] = {};
  auto stage = [&](int r, int c){
    gload_lds(ga + c*32, &As[r][lo]);
    gload_lds(gb + c*32, &Bs[r][lo]);
  };
  auto compute = [&](int r){
    bf8 af = *(const bf8*)&As[r][(w*16 + lr)*32 + q*8];
    #pragma unroll
    for(int t=0;t<4;t++){
      bf8 bfr = *(const bf8*)&Bs[r][(t*16 + lr)*32 + q*8];
      acc[t] = __builtin_amdgcn_mfma_f32_16x16x32_bf16(af, bfr, acc[t], 0,0,0);
    }
  };
  stage(0,0);
  __syncthreads();
  for(int c=1;c<nch;c++){
    stage(c&1, c);
    compute((c-1)&1);
    __syncthreads();
  }
  compute((nch-1)&1);
  #pragma unroll
  for(int t=0;t<4;t++){
    #pragma unroll
    for(int e=0;e<4;e++){
      int gm = m0 + w*16 + q*4 + e;
      int gn = n0 + t*16 + lr;
      float v = acc[t][e]*alpha;
      if(MODE==0) C[cb + (long)gm*ldc + gn] = v;
      else if(MODE==2) C16[cb + (long)gm*ldc + gn] = f2b(v);
      else atomicAdd(&C[cb + (long)gm*ldc + gn], v);
    }
  }
}

// ======== pinv GEMM on bf16 hi/lo pairs — pipelined ping-pong staging ========
__global__ __launch_bounds__(256)
void k_pg3(const u16* __restrict__ Ah, const u16* __restrict__ Al,
           const u16* __restrict__ Bh, const u16* __restrict__ Bl,
           u16* __restrict__ Oh, u16* __restrict__ Ol, float na, float nd,
           u16* __restrict__ TOh, u16* __restrict__ TOl, float ta, float td)
{
  long zo = (long)blockIdx.z*65536;
  int m0 = blockIdx.y*64, n0 = blockIdx.x*64;
  __shared__ u16 S[2][4][2048];
  int tid=threadIdx.x, w=tid>>6, lane=tid&63, q=lane>>4, lr=lane&15;
  int srow=tid>>2, scol=(tid&3)*8;
  long ao = zo + (long)(m0+srow)*256 + scol;
  long bo = zo + (long)(n0+srow)*256 + scol;
  int lo = srow*32 + scol;
  int aoff = (w*16+lr)*32 + q*8;
  f4 acc[4] = {};
  auto stage = [&](int r, int c){
    gload_lds(Ah+ao+c*32, &S[r][0][lo]);
    gload_lds(Al+ao+c*32, &S[r][1][lo]);
    gload_lds(Bh+bo+c*32, &S[r][2][lo]);
    gload_lds(Bl+bo+c*32, &S[r][3][lo]);
  };
  auto compute = [&](int r){
    bf8 ah = *(const bf8*)&S[r][0][aoff];
    bf8 al = *(const bf8*)&S[r][1][aoff];
    #pragma unroll
    for(int t=0;t<4;t++){
      int boff = (t*16+lr)*32 + q*8;
      bf8 bh = *(const bf8*)&S[r][2][boff];
      bf8 bl = *(const bf8*)&S[r][3][boff];
      acc[t] = __builtin_amdgcn_mfma_f32_16x16x32_bf16(ah, bh, acc[t], 0,0,0);
      acc[t] = __builtin_amdgcn_mfma_f32_16x16x32_bf16(ah, bl, acc[t], 0,0,0);
      acc[t] = __builtin_amdgcn_mfma_f32_16x16x32_bf16(al, bh, acc[t], 0,0,0);
    }
  };
  stage(0,0);
  __syncthreads();
  #pragma unroll
  for(int c=1;c<8;c++){
    stage(c&1, c);
    compute((c-1)&1);
    __syncthreads();
  }
  compute(1);
  #pragma unroll
  for(int t=0;t<4;t++){
    int gn = n0 + t*16 + lr;
    if(Oh){
      #pragma unroll
      for(int r=0;r<4;r++){
        int gm = m0 + w*16 + q*4 + r;
        float v = na*acc[t][r] + ((gm==gn)?nd:0.f);
        u16 h = f2b(v);
        long o = zo + (long)gm*256 + gn;
        Oh[o] = h; Ol[o] = f2b(v - b2f(h));
      }
    }
    if(TOh){
      us4 th, tl;
      #pragma unroll
      for(int r=0;r<4;r++){
        int gm = m0 + w*16 + q*4 + r;
        float v = ta*acc[t][r] + ((gm==gn)?td:0.f);
        u16 h = f2b(v);
        th[r] = h; tl[r] = f2b(v - b2f(h));
      }
      long o = zo + (long)gn*256 + (m0 + w*16 + q*4);
      *(us4*)&TOh[o] = th; *(us4*)&TOl[o] = tl;
    }
  }
}

// ======== fused attn1: S=SCALE*q@kl^T; P=softmax(S); Qc=P@zav ========
__global__ __launch_bounds__(256)
void k_att1(const u16* __restrict__ qkv16, const u16* __restrict__ kl,
            const u16* __restrict__ zavT, float* __restrict__ Qc)
{
  int z = blockIdx.y, b = z>>3, h = z&7;
  int m0 = blockIdx.x*64;
  __shared__ u16 SQ[64*64];
  __shared__ u16 SKL[256*64];
  __shared__ u16 SZV[64*256];
  int tid=threadIdx.x, w=tid>>6, lane=tid&63, q=lane>>4, lr=lane&15;
  {
    const u16* qb = qkv16 + (long)b*NP*1536 + h*64;
    #pragma unroll
    for(int p=0;p<2;p++){
      int idx = tid + p*256; int row = idx>>3, c8 = (idx&7)*8;
      gload_lds(qb + (long)(m0+row)*1536 + c8, &SQ[row*64 + c8]);
    }
    const u16* kb = kl + (long)z*16384;
    #pragma unroll
    for(int p=0;p<8;p++){
      int idx = tid + p*256; int row = idx>>3, c8 = (idx&7)*8;
      gload_lds(kb + row*64 + c8, &SKL[row*64 + c8]);
    }
    const u16* zb = zavT + (long)z*16384;
    #pragma unroll
    for(int p=0;p<8;p++){
      int idx = tid + p*256; int row = idx>>5, c8 = (idx&31)*8;
      gload_lds(zb + row*256 + c8, &SZV[row*256 + c8]);
    }
  }
  __syncthreads();
  f4 acc[16] = {};
  {
    bf8 af0 = *(const bf8*)&SQ[(w*16+lr)*64 + q*8];
    bf8 af1 = *(const bf8*)&SQ[(w*16+lr)*64 + 32 + q*8];
    #pragma unroll
    for(int t=0;t<16;t++){
      bf8 b0 = *(const bf8*)&SKL[(t*16+lr)*64 + q*8];
      bf8 b1 = *(const bf8*)&SKL[(t*16+lr)*64 + 32 + q*8];
      acc[t] = __builtin_amdgcn_mfma_f32_16x16x32_bf16(af0, b0, acc[t], 0,0,0);
      acc[t] = __builtin_amdgcn_mfma_f32_16x16x32_bf16(af1, b1, acc[t], 0,0,0);
    }
  }
  float mx[4] = {-1e30f,-1e30f,-1e30f,-1e30f};
  #pragma unroll
  for(int t=0;t<16;t++)
    #pragma unroll
    for(int e=0;e<4;e++) mx[e] = fmaxf(mx[e], acc[t][e]*SCALE);
  #pragma unroll
  for(int s=1;s<16;s<<=1)
    #pragma unroll
    for(int e=0;e<4;e++) mx[e] = fmaxf(mx[e], __shfl_xor(mx[e], s));
  float sm[4] = {0.f,0.f,0.f,0.f};
  #pragma unroll
  for(int t=0;t<16;t++)
    #pragma unroll
    for(int e=0;e<4;e++){ float p = expf(acc[t][e]*SCALE - mx[e]); acc[t][e]=p; sm[e]+=p; }
  #pragma unroll
  for(int s=1;s<16;s<<=1)
    #pragma unroll
    for(int e=0;e<4;e++) sm[e] += __shfl_xor(sm[e], s);
  float inv[4];
  #pragma unroll
  for(int e=0;e<4;e++) inv[e] = 1.f/sm[e];
  __syncthreads();
  u16* PS = SKL;
  #pragma unroll
  for(int t=0;t<16;t++)
    #pragma unroll
    for(int e=0;e<4;e++)
      PS[(w*16 + q*4 + e)*256 + t*16 + lr] = f2b(acc[t][e]*inv[e]);
  __syncthreads();
  f4 acc2[4] = {};
  #pragma unroll
  for(int ks=0;ks<8;ks++){
    bf8 af = *(const bf8*)&PS[(w*16+lr)*256 + ks*32 + q*8];
    #pragma unroll
    for(int t=0;t<4;t++){
      bf8 bf_ = *(const bf8*)&SZV[(t*16+lr)*256 + ks*32 + q*8];
      acc2[t] = __builtin_amdgcn_mfma_f32_16x16x32_bf16(af, bf_, acc2[t], 0,0,0);
    }
  }
  #pragma unroll
  for(int t=0;t<4;t++)
    #pragma unroll
    for(int r=0;r<4;r++){
      int gm = m0 + w*16 + q*4 + r;
      int gd = t*16 + lr;
      Qc[((long)b*NP + gm)*512 + h*64 + gd] = acc2[t][r];
    }
}

// ======== softmax: wave per row, 256 cols, fp32 ========
__global__ __launch_bounds__(256)
void k_smw32(float* __restrict__ X){
  long row = (long)blockIdx.x*4 + (threadIdx.x>>6);
  int lane = threadIdx.x & 63;
  float* p = X + row*256;
  float4 v = *(float4*)&p[lane*4];
  float m = fmaxf(fmaxf(v.x,v.y),fmaxf(v.z,v.w));
  for(int s=32;s;s>>=1) m = fmaxf(m, __shfl_xor(m, s));
  float e0=expf(v.x-m), e1=expf(v.y-m), e2=expf(v.z-m), e3=expf(v.w-m);
  float sum = e0+e1+e2+e3;
  for(int s=32;s;s>>=1) sum += __shfl_xor(sum, s);
  float inv = 1.f/sum;
  float4 o = {e0*inv, e1*inv, e2*inv, e3*inv};
  *(float4*)&p[lane*4] = o;
}

// ======== softmax: block per row, 4352 cols, register-resident bf16 ========
__global__ __launch_bounds__(256)
void k_smb16(u16* __restrict__ X){
  u16* p = X + (long)blockIdx.x*4352;
  int tid=threadIdx.x, lane=tid&63, w=tid>>6;
  __shared__ float xw[4], sw[4];
  float e[17];
  float m = -1e30f;
  #pragma unroll
  for(int i=0;i<17;i++){ e[i] = b2f(p[tid + i*256]); m = fmaxf(m, e[i]); }
  for(int s=32;s;s>>=1) m = fmaxf(m, __shfl_xor(m, s));
  if(lane==0) xw[w] = m;
  __syncthreads();
  m = fmaxf(fmaxf(xw[0],xw[1]), fmaxf(xw[2],xw[3]));
  float sum = 0.f;
  #pragma unroll
  for(int i=0;i<17;i++){ e[i] = expf(e[i]-m); sum += e[i]; }
  for(int s=32;s;s>>=1) sum += __shfl_xor(sum, s);
  if(lane==0) sw[w] = sum;
  __syncthreads();
  sum = sw[0]+sw[1]+sw[2]+sw[3];
  float inv = 1.f/sum;
  #pragma unroll
  for(int i=0;i<17;i++) p[tid + i*256] = f2b(e[i]*inv);
}

// weight transpose+convert: in fp32 [K][N] -> out bf16 [N][K]
__global__ void k_wT(const float* __restrict__ in, u16* __restrict__ out, int K, int N){
  int n0=blockIdx.x*32, k0=blockIdx.y*32, tid=threadIdx.x;
  __shared__ float T[32][33];
  int lr=tid&31, lc=tid>>5;
  #pragma unroll
  for(int p=0;p<4;p++) T[lc+8*p][lr] = in[(long)(k0+lc+8*p)*N + n0+lr];
  __syncthreads();
  #pragma unroll
  for(int p=0;p<4;p++) out[(long)(n0+lc+8*p)*K + k0+lr] = f2b(T[lr][lc+8*p]);
}

// v^T: qkvb16 v-section [NP][64] per (b,h) -> vT [b][h][64][NP]
__global__ __launch_bounds__(256)
void k_vT(const u16* __restrict__ qkv16, u16* __restrict__ vT){
  int t0=blockIdx.x*64, h=blockIdx.y, b=blockIdx.z, tid=threadIdx.x;
  __shared__ u16 T[64][72];
  const u16* src = qkv16 + (long)b*NP*1536 + 1024 + h*64;
  for(int s=0;s<2;s++){
    int idx=tid+s*256; int row=idx>>3, c8=(idx&7)*8;
    *(us8*)&T[row][c8] = *(const us8*)&src[(long)(t0+row)*1536 + c8];
  }
  __syncthreads();
  u16* dst = vT + ((long)(b*8+h)*64)*NP;
  int d = tid>>2, j0=(tid&3)*16;
  us8 v0,v1;
  #pragma unroll
  for(int jj=0;jj<8;jj++){ v0[jj]=T[j0+jj][d]; v1[jj]=T[j0+8+jj][d]; }
  *(us8*)&dst[(long)d*NP + t0 + j0]     = v0;
  *(us8*)&dst[(long)d*NP + t0 + j0 + 8] = v1;
}

__global__ void k_cvt16(const float* __restrict__ in, u16* __restrict__ out, long n){
  long i = (long)blockIdx.x*256 + threadIdx.x;
  if(i<n) out[i] = f2b(in[i]);
}

__global__ void k_zero(float* __restrict__ p, long n){
  long i = (long)blockIdx.x*256 + threadIdx.x;
  if(i<n) p[i] = 0.f;
}

__global__ void k_cls(const float* __restrict__ cls, float* __restrict__ seq){
  int b = blockIdx.x;
  seq[(long)b*NTOK*EMB + threadIdx.x] = cls[threadIdx.x];
}

// LayerNorm of seq into xpb bf16 with 255 zero rows at front
__global__ void k_ln_pad(const float* __restrict__ seq, u16* __restrict__ xp,
                         const float* __restrict__ g, const float* __restrict__ bb){
  int b = blockIdx.y, i = blockIdx.x, tid = threadIdx.x;
  u16* out = xp + ((long)b*NP + i)*EMB;
  if(i < PADF){ out[tid]=0; out[tid+256]=0; return; }
  const float* x = seq + ((long)b*NTOK + (i-PADF))*EMB;
  float v0 = x[tid], v1 = x[tid+256];
  __shared__ float red[256];
  red[tid]=v0+v1; __syncthreads();
  for(int s=128;s>0;s>>=1){ if(tid<s) red[tid]+=red[tid+s]; __syncthreads(); }
  float mu = red[0]*(1.0f/512.0f); __syncthreads();
  float d0=v0-mu, d1=v1-mu;
  red[tid]=d0*d0+d1*d1; __syncthreads();
  for(int s=128;s>0;s>>=1){ if(tid<s) red[tid]+=red[tid+s]; __syncthreads(); }
  float rstd = rsqrtf(red[0]*(1.0f/512.0f) + 1e-5f);
  out[tid]     = f2b(d0*rstd*g[tid]     + bb[tid]);
  out[tid+256] = f2b(d1*rstd*g[tid+256] + bb[tid+256]);
}

__global__ void k_landmarks(const u16* __restrict__ qkv, u16* __restrict__ q_l, u16* __restrict__ k_l){
  int j = blockIdx.x, h = blockIdx.y, b = blockIdx.z, d = threadIdx.x;
  const u16* base = qkv + (long)b*NP*1536 + h*64 + d;
  float sq=0.f, sk=0.f;
  for(int l=0;l<17;l++){
    long row = (long)(j*17+l)*1536;
    sq += b2f(base[row]);
    sk += b2f(base[row+512]);
  }
  long o = (((long)b*HEADS + h)*LM + j)*DH + d;
  q_l[o] = f2b(sq * (SCALE/17.0f));
  k_l[o] = f2b(sk * (1.0f/17.0f));
}

__global__ void k_pinv_norm(const float* __restrict__ A2, float* __restrict__ rmax, float* __restrict__ cmax){
  int z = blockIdx.x, tid = threadIdx.x;
  const float* X = A2 + (long)z*65536;
  float rs=0.f, cs=0.f;
  for(int j=0;j<256;j++){ rs += fabsf(X[tid*256+j]); cs += fabsf(X[j*256+tid]); }
  __shared__ float r1[256], r2[256];
  r1[tid]=rs; r2[tid]=cs; __syncthreads();
  for(int s=128;s>0;s>>=1){ if(tid<s){ r1[tid]=fmaxf(r1[tid],r1[tid+s]); r2[tid]=fmaxf(r2[tid],r2[tid+s]); } __syncthreads(); }
  if(tid==0){ rmax[z]=r1[0]; cmax[z]=r2[0]; }
}

__global__ void k_pair_init(const float* __restrict__ att2,
    const float* __restrict__ rmax, const float* __restrict__ cmax,
    u16* __restrict__ Xh, u16* __restrict__ Xl,
    u16* __restrict__ Zh, u16* __restrict__ Zl,
    u16* __restrict__ Zth, u16* __restrict__ Ztl)
{
  long zo = (long)blockIdx.z*65536;
  int i0 = blockIdx.y*64, j0 = blockIdx.x*64;
  float rm=0.f, cm=0.f;
  for(int t=0;t<16;t++){ rm=fmaxf(rm,rmax[t]); cm=fmaxf(cm,cmax[t]); }
  float inv = 1.0f/(rm*cm);
  __shared__ float T[64][68];
  int tid = threadIdx.x;
  int li = tid>>2, jc = (tid&3)*16;
  #pragma unroll
  for(int u=0;u<4;u++){
    float4 v = *(const float4*)&att2[zo + (long)(i0+li)*256 + j0 + jc + u*4];
    T[li][jc+u*4]=v.x; T[li][jc+u*4+1]=v.y; T[li][jc+u*4+2]=v.z; T[li][jc+u*4+3]=v.w;
    long o = zo + (long)(i0+li)*256 + j0 + jc + u*4;
    float vv[4] = {v.x,v.y,v.z,v.w};
    us4 xh, xl, zth, ztl;
    #pragma unroll
    for(int c=0;c<4;c++){
      u16 h = f2b(vv[c]); xh[c]=h; xl[c]=f2b(vv[c]-b2f(h));
      float zt = vv[c]*inv;
      u16 h2 = f2b(zt); zth[c]=h2; ztl[c]=f2b(zt-b2f(h2));
    }
    *(us4*)&Xh[o]=xh; *(us4*)&Xl[o]=xl; *(us4*)&Zth[o]=zth; *(us4*)&Ztl[o]=ztl;
  }
  __syncthreads();
  int lj = tid>>2, ic = (tid&3)*16;
  #pragma unroll
  for(int r=0;r<16;r++){
    float x = T[ic+r][lj]*inv;
    u16 h = f2b(x);
    long o = zo + (long)(j0+lj)*256 + i0 + ic + r;
    Zh[o]=h; Zl[o]=f2b(x-b2f(h));
  }
}

// res conv + fused bf16 convert: Qc16 = bf16(Qc + dwconv(v))
__global__ __launch_bounds__(256)
void k_rconv(const u16* __restrict__ qkv16, const float* __restrict__ resk,
             const float* __restrict__ Qin, u16* __restrict__ Qo16){
  int t0 = blockIdx.x*64, h = blockIdx.y, b = blockIdx.z;
  __shared__ float V[96*64];
  const u16* vb = qkv16 + (long)b*NP*1536 + 1024 + h*64;
  int tid = threadIdx.x;
  #pragma unroll
  for(int s=0;s<3;s++){
    int idx = tid + s*256;
    int row = idx>>3, c8 = (idx&7)*8;
    int p = t0 - 16 + row;
    if(p>=0 && p<NP){
      us8 v = *(const us8*)&vb[(long)p*1536 + c8];
      #pragma unroll
      for(int jj=0;jj<8;jj++) V[row*64+c8+jj] = b2f(v[jj]);
    } else {
      #pragma unroll
      for(int jj=0;jj<8;jj++) V[row*64+c8+jj] = 0.f;
    }
  }
  __syncthreads();
  int d = tid&63, lt = (tid>>6)*16;
  float acc[16] = {};
  #pragma unroll
  for(int s=0;s<48;s++){
    float val = V[(lt+s)*64 + d];
    #pragma unroll
    for(int j=0;j<16;j++){
      int tap = s - j;
      if(tap>=0 && tap<33) acc[j] += resk[h*33+tap]*val;
    }
  }
  #pragma unroll
  for(int j=0;j<16;j++){
    long idx = ((long)b*NP + t0 + lt + j)*EMB + h*64 + d;
    Qo16[idx] = f2b(Qin[idx] + acc[j]);
  }
}

// PPEG: 64-ch groups, 4 rows x 64 ch per block, x-split 2; grid (32, 8, 2)
__global__ __launch_bounds__(256)
void k_ppeg(const float* __restrict__ seq, float* __restrict__ out,
    const float* __restrict__ w7,const float* __restrict__ b7,
    const float* __restrict__ w5,const float* __restrict__ b5,
    const float* __restrict__ w3,const float* __restrict__ b3){
  int b = blockIdx.z, cg = blockIdx.y;
  int rp = blockIdx.x>>1, xs = blockIdx.x&1;
  int ch0 = cg*64;
  __shared__ float s7[64*49], s5[64*25], s3[64*9], sbias[64];
  int tid = threadIdx.x;
  for(int i=tid;i<64*49;i+=256) s7[i] = w7[ch0*49+i];
  for(int i=tid;i<64*25;i+=256) s5[i] = w5[ch0*25+i];
  for(int i=tid;i<64*9;i+=256)  s3[i] = w3[ch0*9+i];
  if(tid<64) sbias[tid] = b7[ch0+tid]+b5[ch0+tid]+b3[ch0+tid];
  if(cg==0 && blockIdx.x==0){
    out[(long)b*NTOK*EMB + tid]       = seq[(long)b*NTOK*EMB + tid];
    out[(long)b*NTOK*EMB + 256 + tid] = seq[(long)b*NTOK*EMB + 256 + tid];
  }
  __syncthreads();
  int c = tid & 63;
  int y = rp*4 + (tid>>6);
  const float* sbase = seq + (long)b*NTOK*EMB + EMB + (ch0 + c);
  float* obase = out + (long)b*NTOK*EMB + EMB + (ch0 + c);
  const float* W7 = &s7[c*49];
  const float* W5 = &s5[c*25];
  const float* W3 = &s3[c*9];
  float bsum = sbias[c];
  for(int xc=0;xc<4;xc++){
    int xb = xs*32 + xc*8;
    float acc[8];
    #pragma unroll
    for(int j=0;j<8;j++) acc[j] = sbase[(long)(y*64+xb+j)*EMB] + bsum;
    #pragma unroll
    for(int dy=-3;dy<=3;dy++){
      int yy = y+dy;
      if(yy<0||yy>=64) continue;
      float v[14];
      #pragma unroll
      for(int u=0;u<14;u++){
        int xx = xb + u - 3;
        v[u] = (xx>=0 && xx<64) ? sbase[(long)(yy*64+xx)*EMB] : 0.f;
      }
      #pragma unroll
      for(int dx=-3;dx<=3;dx++){
        float wsum = W7[(dy+3)*7+(dx+3)];
        if(dy>=-2&&dy<=2&&dx>=-2&&dx<=2) wsum += W5[(dy+2)*5+(dx+2)];
        if(dy>=-1&&dy<=1&&dx>=-1&&dx<=1) wsum += W3[(dy+1)*3+(dx+1)];
        #pragma unroll
        for(int j=0;j<8;j++) acc[j] += v[j+dx+3]*wsum;
      }
    }
    #pragma unroll
    for(int j=0;j<8;j++) obase[(long)(y*64+xb+j)*EMB] = acc[j];
  }
}

__global__ void k_final_ln(const float* __restrict__ seq, const float* __restrict__ g,
                           const float* __restrict__ bb, float* __restrict__ out){
  int b = blockIdx.x, tid = threadIdx.x;
  const float* x = seq + (long)b*NTOK*EMB;
  float v0 = x[tid], v1 = x[tid+256];
  __shared__ float red[256];
  red[tid]=v0+v1; __syncthreads();
  for(int s=128;s>0;s>>=1){ if(tid<s) red[tid]+=red[tid+s]; __syncthreads(); }
  float mu = red[0]*(1.0f/512.0f); __syncthreads();
  float d0=v0-mu, d1=v1-mu;
  red[tid]=d0*d0+d1*d1; __syncthreads();
  for(int s=128;s>0;s>>=1){ if(tid<s) red[tid]+=red[tid+s]; __syncthreads(); }
  float rstd = rsqrtf(red[0]*(1.0f/512.0f) + 1e-5f);
  out[b*512+tid]     = d0*rstd*g[tid]     + bb[tid];
  out[b*512+tid+256] = d1*rstd*g[tid+256] + bb[tid+256];
}

// ---------------- host ----------------
extern "C" void kernel_launch(void* const* d_in, const int* in_sizes, int n_in,
                              void* d_out, int out_size, void* d_ws, size_t ws_size,
                              hipStream_t stream) {
  const float* in[24];
  for(int i=0;i<24;i++) in[i] = (const float*)d_in[i];

  float* W = (float*)d_ws;
  size_t off = 0;
  float* seqA = W+off; off += 4195328;        // 2*4097*512
  float* seqB = W+off; off += 4195328;
  float* att2 = W+off; off += 1048576;        // 16*65536
  float* Qc   = W+off; off += 4456448;        // 2*4352*512
  float* avbT = W+off; off += 262144;         // 16*64*256
  u16* xpb    = (u16*)(W+off); off += 2228224;  // 2*4352*512 u16
  u16* qkvb16 = (u16*)(W+off); off += 6684672;  // 2*4352*1536 u16
  u16* vT16   = (u16*)(W+off); off += 2228224;
  u16* q_l16  = (u16*)(W+off); off += 131072;   // 16*256*64 u16
  u16* k_l16  = (u16*)(W+off); off += 131072;
  u16* sc16   = (u16*)(W+off); off += 8912896;  // 16*256*4352 u16
  u16* avbT16 = (u16*)(W+off); off += 131072;
  u16* zavT16 = (u16*)(W+off); off += 131072;
  u16* Qc16   = (u16*)(W+off); off += 2228224;
  u16* qkvwT1 = (u16*)(W+off); off += 393216;   // 1536*512 u16
  u16* qkvwT2 = (u16*)(W+off); off += 393216;
  u16* outwT1 = (u16*)(W+off); off += 131072;   // 512*512 u16
  u16* outwT2 = (u16*)(W+off); off += 131072;
  u16* pairs  = (u16*)(W+off); off += 9437184;  // 18*16*65536 u16
  float* rmax = W+off; off += 16;
  float* cmax = W+off; off += 16;
  if (ws_size < off*sizeof(float)) return;

  u16* h16   = sc16;                  // aliased (sc16 written later)
  u16* wfc1T = sc16 + 8388608;

  const long PB = 1048576;  // 16*65536
  u16 *Xh=pairs, *Xl=pairs+PB;
  u16 *Z0h=pairs+2*PB, *Z0l=pairs+3*PB, *Z0th=pairs+4*PB, *Z0tl=pairs+5*PB;
  u16 *Z1h=pairs+6*PB, *Z1l=pairs+7*PB, *Z1th=pairs+8*PB, *Z1tl=pairs+9*PB;
  u16 *Ph=pairs+10*PB, *Pl=pairs+11*PB;
  u16 *Tth=pairs+12*PB, *Ttl=pairs+13*PB;
  u16 *Uth=pairs+14*PB, *Utl=pairs+15*PB;
  u16 *Vth=pairs+16*PB, *Vtl=pairs+17*PB;

  // weight conversions/transposes
  k_cvt16<<<32768,256,0,stream>>>(in[0], h16, 8388608L);
  k_wT<<<dim3(16,32),256,0,stream>>>(in[1],  wfc1T, 1024, 512);
  k_wT<<<dim3(48,16),256,0,stream>>>(in[6],  qkvwT1, 512, 1536);
  k_wT<<<dim3(48,16),256,0,stream>>>(in[18], qkvwT2, 512, 1536);
  k_wT<<<dim3(16,16),256,0,stream>>>(in[7],  outwT1, 512, 512);
  k_wT<<<dim3(16,16),256,0,stream>>>(in[19], outwT2, 512, 512);

  // fc1 + cls
  k_g128<0><<<dim3(4,32,2),256,0,stream>>>(h16, wfc1T, seqA+EMB, nullptr,
      1024, 1024,1024,512, 4194304L,0, 0,0, (long)NTOK*EMB,0, 1, 1.0f, in[2], 1, 0, 4, 1);
  k_cls<<<2,512,0,stream>>>(in[3], seqA);

  auto attention = [&](float* seq, const float* lng,const float* lnb,
                       const u16* qkvwT, const u16* outwT, const float* outb, const float* resk){
    k_ln_pad<<<dim3(NP,2),256,0,stream>>>(seq, xpb, lng, lnb);
    k_g128<2><<<dim3(12,34,2),256,0,stream>>>(xpb, qkvwT, nullptr, qkvb16,
        512, 512,512,1536, (long)NP*512,0, 0,0, (long)NP*1536,0, 1, 1.0f, nullptr, 0, 0, 12, 1);
    k_landmarks<<<dim3(LM,HEADS,2),64,0,stream>>>(qkvb16, q_l16, k_l16);
    k_vT<<<dim3(68,8,2),256,0,stream>>>(qkvb16, vT16);
    // attn2 = softmax(q_l @ k_l^T)  (fp32 scores for pinv)
    k_g128<0><<<dim3(2,2,16),256,0,stream>>>(q_l16, k_l16, att2, nullptr,
        64, 64,64,256, 0,16384, 0,16384, 0,65536, 16, 1.0f, nullptr, 0, 0, 2, 1);
    k_smw32<<<1024,256,0,stream>>>(att2);
    // pinv on bf16 pairs
    k_pinv_norm<<<16,256,0,stream>>>(att2, rmax, cmax);
    k_pair_init<<<dim3(4,4,16),256,0,stream>>>(att2, rmax, cmax, Xh,Xl, Z0h,Z0l, Z0th,Z0tl);
    dim3 pgrid(4,4,16);
    for(int it=0; it<6; it++){
      u16 *Zh_=(it&1)?Z1h:Z0h, *Zl_=(it&1)?Z1l:Z0l, *Zth_=(it&1)?Z1th:Z0th, *Ztl_=(it&1)?Z1tl:Z0tl;
      u16 *Nh_=(it&1)?Z0h:Z1h, *Nl_=(it&1)?Z0l:Z1l, *Nth_=(it&1)?Z0th:Z1th, *Ntl_=(it&1)?Z0tl:Z1tl;
      k_pg3<<<pgrid,256,0,stream>>>(Xh,Xl, Zth_,Ztl_, Ph,Pl,1.0f,0.f, Tth,Ttl,-1.0f,7.f);
      k_pg3<<<pgrid,256,0,stream>>>(Ph,Pl, Tth,Ttl, nullptr,nullptr,0.f,0.f, Uth,Utl,-1.0f,15.f);
      k_pg3<<<pgrid,256,0,stream>>>(Ph,Pl, Uth,Utl, nullptr,nullptr,0.f,0.f, Vth,Vtl,-1.0f,13.f);
      if(it<5) k_pg3<<<pgrid,256,0,stream>>>(Zh_,Zl_, Vth,Vtl, Nh_,Nl_,0.25f,0.f, Nth_,Ntl_,0.25f,0.f);
      else     k_pg3<<<pgrid,256,0,stream>>>(Zh_,Zl_, Vth,Vtl, Nh_,Nl_,0.25f,0.f, nullptr,nullptr,0.f,0.f);
    }
    // attn3 scores = q_l @ k^T -> sc16 (bf16)
    k_g128<2><<<dim3(34,2,16),256,0,stream>>>(q_l16, qkvb16+512, nullptr, sc16,
        64, 64,1536,4352, 131072L,16384, (long)NP*1536,64, 8L*LM*NP,(long)LM*NP, 8, 1.0f, nullptr, 0, 0, 34, 1);
    k_smb16<<<4096,256,0,stream>>>(sc16);
    // avbT = v^T @ attn3_sm^T (split-K atomic)
    k_zero<<<1024,256,0,stream>>>(avbT, 262144L);
    k_g64<3><<<dim3(4*17,1,16),256,0,stream>>>(vT16, sc16, avbT, nullptr,
        4352, 4352,4352,256, 2228224L,278528L, 8L*LM*NP,(long)LM*NP, 131072L,16384L, 8, 1.0f, 4, 17);
    k_cvt16<<<1024,256,0,stream>>>(avbT, avbT16, 262144L);
    // zavT = avbT @ Z^T  -> bf16
    k_g64<2><<<dim3(4,1,16),256,0,stream>>>(avbT16, Z0h, nullptr, zavT16,
        256, 256,256,256, 0,16384L, 0,65536L, 0,16384L, 16, 1.0f, 4, 1);
    // fused attn1: scores + softmax + @zav -> Qc
    k_att1<<<dim3(68,16),256,0,stream>>>(qkvb16, k_l16, zavT16, Qc);
    // res conv fused with bf16 convert
    k_rconv<<<dim3(68,8,2),256,0,stream>>>(qkvb16, resk, Qc, Qc16);
    // out proj + residual add into seq (split-K=2, atomic, bias on kc==0)
    k_g128<4><<<dim3(8,34,2),256,0,stream>>>(Qc16, outwT, seq, nullptr,
        512, 512,512,512, (long)NP*512,0, 0,0, (long)NTOK*EMB,0, 1, 1.0f, outb, 0, PADF, 4, 2);
  };

  attention(seqA, in[4], in[5], qkvwT1, outwT1, in[8], in[9]);
  k_ppeg<<<dim3(32,8,2),256,0,stream>>>(seqA, seqB, in[10],in[11],in[12],in[13],in[14],in[15]);
  attention(seqB, in[16], in[17], qkvwT2, outwT2, in[20], in[21]);
  k_final_ln<<<2,256,0,stream>>>(seqB, in[22], in[23], (float*)d_out);
}

// Round 13
// 1091.208 us; speedup vs baseline: 1.1498x; 1.0066x over previous
//
#include <hip/hip_runtime.h>
#include <hip/hip_bf16.h>

#define HEADS 8
#define DH 64
#define EMB 512
#define NP 4352
#define NTOK 4097
#define PADF 255
#define LM 256
#define SCALE 0.125f

typedef __attribute__((ext_vector_type(8))) short bf8;
typedef __attribute__((ext_vector_type(4))) float f4;
typedef __attribute__((ext_vector_type(8))) unsigned short us8;
typedef __attribute__((ext_vector_type(4))) unsigned short us4;
typedef unsigned short u16;

__device__ __forceinline__ u16 f2b(float f){
  union { float f; unsigned u; } x; x.f = f;
  unsigned r = x.u + 0x7fffu + ((x.u>>16)&1u);
  return (u16)(r>>16);
}
__device__ __forceinline__ float b2f(u16 h){
  union { unsigned u; float f; } x; x.u = ((unsigned)h)<<16;
  return x.f;
}

__device__ __forceinline__ void gload_lds(const u16* g, u16* l){
  __builtin_amdgcn_global_load_lds((const __attribute__((address_space(1))) void*)g,
                                   (__attribute__((address_space(3))) void*)l, 16, 0, 0);
}

// ======== 128x128 NT bf16 GEMM, BK=32, ping-pong pipelined staging ========
// MODE 0: fp32 store; MODE 2: bf16 store; MODE 3: fp32 C[gm-rowoff] += v;
// MODE 4: fp32 atomicAdd to C[gm-rowoff] (split-K safe; bias only on kc==0)
template<int MODE>
__global__ __launch_bounds__(256)
void k_g128(const u16* __restrict__ A, const u16* __restrict__ B,
            float* __restrict__ C, u16* __restrict__ C16,
            int K, int lda, int ldb, int ldc,
            long sAb, long sAh, long sBb, long sBh, long sCb, long sCh, int nh,
            float alpha, const float* __restrict__ bias, int relu, int rowoff,
            int nx, int ksplit)
{
  int z = blockIdx.z;
  const u16* Ab = A + (long)(z/nh)*sAb + (long)(z%nh)*sAh;
  const u16* Bb = B + (long)(z/nh)*sBb + (long)(z%nh)*sBh;
  long cb = (long)(z/nh)*sCb + (long)(z%nh)*sCh;
  int bx = blockIdx.x % nx, kc = blockIdx.x / nx;
  int m0 = blockIdx.y*128, n0 = bx*128;
  int klen = K/ksplit, kbeg = kc*klen, nch = klen/32;
  __shared__ u16 As[2][4096];
  __shared__ u16 Bs[2][4096];
  int tid=threadIdx.x, w=tid>>6, lane=tid&63, q=lane>>4, lr=lane&15;
  int wrow=(w>>1)*64, wcol=(w&1)*64;
  int srow = tid>>2, scol = (tid&3)*8;
  const u16* ga  = Ab + (long)(m0+srow)*lda + kbeg + scol;
  const u16* ga2 = Ab + (long)(m0+64+srow)*lda + kbeg + scol;
  const u16* gb  = Bb + (long)(n0+srow)*ldb + kbeg + scol;
  const u16* gb2 = Bb + (long)(n0+64+srow)*ldb + kbeg + scol;
  int lo = srow*32 + scol;
  f4 acc[4][4] = {};
  auto stage = [&](int r, int c){
    gload_lds(ga  + c*32, &As[r][lo]);
    gload_lds(ga2 + c*32, &As[r][2048+lo]);
    gload_lds(gb  + c*32, &Bs[r][lo]);
    gload_lds(gb2 + c*32, &Bs[r][2048+lo]);
  };
  auto compute = [&](int r){
    bf8 af[4], bfr[4];
    #pragma unroll
    for(int rr=0;rr<4;rr++) af[rr]  = *(const bf8*)&As[r][(wrow + rr*16 + lr)*32 + q*8];
    #pragma unroll
    for(int t=0;t<4;t++) bfr[t] = *(const bf8*)&Bs[r][(wcol + t*16 + lr)*32 + q*8];
    #pragma unroll
    for(int rr=0;rr<4;rr++)
      #pragma unroll
      for(int t=0;t<4;t++)
        acc[rr][t] = __builtin_amdgcn_mfma_f32_16x16x32_bf16(af[rr], bfr[t], acc[rr][t], 0,0,0);
  };
  stage(0,0);
  __syncthreads();
  for(int c=1;c<nch;c++){
    stage(c&1, c);
    compute((c-1)&1);
    __syncthreads();
  }
  compute((nch-1)&1);
  #pragma unroll
  for(int r=0;r<4;r++){
    #pragma unroll
    for(int t=0;t<4;t++){
      #pragma unroll
      for(int e=0;e<4;e++){
        int gm = m0 + wrow + r*16 + q*4 + e;
        int gn = n0 + wcol + t*16 + lr;
        float v = acc[r][t][e]*alpha;
        if(MODE==4){
          if(bias && kc==0) v += bias[gn];
          if(gm>=rowoff) atomicAdd(&C[cb + (long)(gm-rowoff)*ldc + gn], v);
        } else {
          if(bias) v += bias[gn];
          if(relu) v = fmaxf(v,0.f);
          if(MODE==0) C[cb + (long)gm*ldc + gn] = v;
          else if(MODE==2) C16[cb + (long)gm*ldc + gn] = f2b(v);
          else { if(gm>=rowoff) C[cb + (long)(gm-rowoff)*ldc + gn] += v; }
        }
      }
    }
  }
}

// ======== 64x64 NT bf16 GEMM, split-K capable, ping-pong pipelined ========
// MODE 0: fp32 store; MODE 2: bf16 store; MODE 3: fp32 atomicAdd
template<int MODE>
__global__ __launch_bounds__(256)
void k_g64(const u16* __restrict__ A, const u16* __restrict__ B,
           float* __restrict__ C, u16* __restrict__ C16,
           int K, int lda, int ldb, int ldc,
           long sAb, long sAh, long sBb, long sBh, long sCb, long sCh, int nh,
           float alpha, int nx, int ksplit)
{
  int z = blockIdx.z;
  const u16* Ab = A + (long)(z/nh)*sAb + (long)(z%nh)*sAh;
  const u16* Bb = B + (long)(z/nh)*sBb + (long)(z%nh)*sBh;
  long cb = (long)(z/nh)*sCb + (long)(z%nh)*sCh;
  int bx = blockIdx.x % nx, kc = blockIdx.x / nx;
  int m0 = blockIdx.y*64, n0 = bx*64;
  int klen = K/ksplit, kbeg = kc*klen, nch = klen/32;
  __shared__ u16 As[2][2048];
  __shared__ u16 Bs[2][2048];
  int tid=threadIdx.x, w=tid>>6, lane=tid&63, q=lane>>4, lr=lane&15;
  int srow = tid>>2, scol = (tid&3)*8;
  const u16* ga = Ab + (long)(m0+srow)*lda + kbeg + scol;
  const u16* gb = Bb + (long)(n0+srow)*ldb + kbeg + scol;
  int lo = srow*32 + scol;
  f4 acc[4] = {};
  auto stage = [&](int r, int c){
    gload_lds(ga + c*32, &As[r][lo]);
    gload_lds(gb + c*32, &Bs[r][lo]);
  };
  auto compute = [&](int r){
    bf8 af = *(const bf8*)&As[r][(w*16 + lr)*32 + q*8];
    #pragma unroll
    for(int t=0;t<4;t++){
      bf8 bfr = *(const bf8*)&Bs[r][(t*16 + lr)*32 + q*8];
      acc[t] = __builtin_amdgcn_mfma_f32_16x16x32_bf16(af, bfr, acc[t], 0,0,0);
    }
  };
  stage(0,0);
  __syncthreads();
  for(int c=1;c<nch;c++){
    stage(c&1, c);
    compute((c-1)&1);
    __syncthreads();
  }
  compute((nch-1)&1);
  #pragma unroll
  for(int t=0;t<4;t++){
    #pragma unroll
    for(int e=0;e<4;e++){
      int gm = m0 + w*16 + q*4 + e;
      int gn = n0 + t*16 + lr;
      float v = acc[t][e]*alpha;
      if(MODE==0) C[cb + (long)gm*ldc + gn] = v;
      else if(MODE==2) C16[cb + (long)gm*ldc + gn] = f2b(v);
      else atomicAdd(&C[cb + (long)gm*ldc + gn], v);
    }
  }
}

// ======== pinv GEMM on bf16 hi/lo pairs — 32x64 strips, 2 blocks/CU ========
// grid (4, 8, 16). Block 256 thr; wave w: m-tile (w>>1)*16, n-half (w&1)*32.
// LDS flat chunk: [0..1024)=Ah(32x32) [1024..2048)=Al [2048..4096)=Bh(64x32) [4096..6144)=Bl
__global__ __launch_bounds__(256)
void k_pg3(const u16* __restrict__ Ah, const u16* __restrict__ Al,
           const u16* __restrict__ Bh, const u16* __restrict__ Bl,
           u16* __restrict__ Oh, u16* __restrict__ Ol, float na, float nd,
           u16* __restrict__ TOh, u16* __restrict__ TOl, float ta, float td)
{
  long zo = (long)blockIdx.z*65536;
  int m0 = blockIdx.y*32, n0 = blockIdx.x*64;
  __shared__ u16 S[2][6144];
  int tid=threadIdx.x, w=tid>>6, lane=tid&63, q=lane>>4, lr=lane&15;
  // issue-0 source: tid<128 -> Ah rows, tid>=128 -> Al rows
  int t2 = tid & 127;
  const u16* srcA = (tid<128 ? Ah : Al) + zo + (long)(m0 + (t2>>2))*256 + (t2&3)*8;
  const u16* srcBh = Bh + zo + (long)(n0 + (tid>>2))*256 + (tid&3)*8;
  const u16* srcBl = Bl + zo + (long)(n0 + (tid>>2))*256 + (tid&3)*8;
  f4 acc[2] = {};
  auto stage = [&](int r, int c){
    gload_lds(srcA  + c*32, &S[r][tid*8]);
    gload_lds(srcBh + c*32, &S[r][2048 + tid*8]);
    gload_lds(srcBl + c*32, &S[r][4096 + tid*8]);
  };
  int mrow = (w>>1)*16 + lr;
  auto compute = [&](int r){
    bf8 ah = *(const bf8*)&S[r][mrow*32 + q*8];
    bf8 al = *(const bf8*)&S[r][1024 + mrow*32 + q*8];
    #pragma unroll
    for(int t=0;t<2;t++){
      int nrow = (w&1)*32 + t*16 + lr;
      bf8 bh = *(const bf8*)&S[r][2048 + nrow*32 + q*8];
      bf8 bl = *(const bf8*)&S[r][4096 + nrow*32 + q*8];
      acc[t] = __builtin_amdgcn_mfma_f32_16x16x32_bf16(ah, bh, acc[t], 0,0,0);
      acc[t] = __builtin_amdgcn_mfma_f32_16x16x32_bf16(ah, bl, acc[t], 0,0,0);
      acc[t] = __builtin_amdgcn_mfma_f32_16x16x32_bf16(al, bh, acc[t], 0,0,0);
    }
  };
  stage(0,0);
  __syncthreads();
  #pragma unroll
  for(int c=1;c<8;c++){
    stage(c&1, c);
    compute((c-1)&1);
    __syncthreads();
  }
  compute(1);
  #pragma unroll
  for(int t=0;t<2;t++){
    int gn = n0 + (w&1)*32 + t*16 + lr;
    if(Oh){
      #pragma unroll
      for(int r=0;r<4;r++){
        int gm = m0 + (w>>1)*16 + q*4 + r;
        float v = na*acc[t][r] + ((gm==gn)?nd:0.f);
        u16 h = f2b(v);
        long o = zo + (long)gm*256 + gn;
        Oh[o] = h; Ol[o] = f2b(v - b2f(h));
      }
    }
    if(TOh){
      us4 th, tl;
      #pragma unroll
      for(int r=0;r<4;r++){
        int gm = m0 + (w>>1)*16 + q*4 + r;
        float v = ta*acc[t][r] + ((gm==gn)?td:0.f);
        u16 h = f2b(v);
        th[r] = h; tl[r] = f2b(v - b2f(h));
      }
      long o = zo + (long)gn*256 + (m0 + (w>>1)*16 + q*4);
      *(us4*)&TOh[o] = th; *(us4*)&TOl[o] = tl;
    }
  }
}

// ======== fused attn1: S=SCALE*q@kl^T; P=softmax(S); Qc=P@zav ========
__global__ __launch_bounds__(256)
void k_att1(const u16* __restrict__ qkv16, const u16* __restrict__ kl,
            const u16* __restrict__ zavT, float* __restrict__ Qc)
{
  int z = blockIdx.y, b = z>>3, h = z&7;
  int m0 = blockIdx.x*64;
  __shared__ u16 SQ[64*64];
  __shared__ u16 SKL[256*64];
  __shared__ u16 SZV[64*256];
  int tid=threadIdx.x, w=tid>>6, lane=tid&63, q=lane>>4, lr=lane&15;
  {
    const u16* qb = qkv16 + (long)b*NP*1536 + h*64;
    #pragma unroll
    for(int p=0;p<2;p++){
      int idx = tid + p*256; int row = idx>>3, c8 = (idx&7)*8;
      gload_lds(qb + (long)(m0+row)*1536 + c8, &SQ[row*64 + c8]);
    }
    const u16* kb = kl + (long)z*16384;
    #pragma unroll
    for(int p=0;p<8;p++){
      int idx = tid + p*256; int row = idx>>3, c8 = (idx&7)*8;
      gload_lds(kb + row*64 + c8, &SKL[row*64 + c8]);
    }
    const u16* zb = zavT + (long)z*16384;
    #pragma unroll
    for(int p=0;p<8;p++){
      int idx = tid + p*256; int row = idx>>5, c8 = (idx&31)*8;
      gload_lds(zb + row*256 + c8, &SZV[row*256 + c8]);
    }
  }
  __syncthreads();
  f4 acc[16] = {};
  {
    bf8 af0 = *(const bf8*)&SQ[(w*16+lr)*64 + q*8];
    bf8 af1 = *(const bf8*)&SQ[(w*16+lr)*64 + 32 + q*8];
    #pragma unroll
    for(int t=0;t<16;t++){
      bf8 b0 = *(const bf8*)&SKL[(t*16+lr)*64 + q*8];
      bf8 b1 = *(const bf8*)&SKL[(t*16+lr)*64 + 32 + q*8];
      acc[t] = __builtin_amdgcn_mfma_f32_16x16x32_bf16(af0, b0, acc[t], 0,0,0);
      acc[t] = __builtin_amdgcn_mfma_f32_16x16x32_bf16(af1, b1, acc[t], 0,0,0);
    }
  }
  float mx[4] = {-1e30f,-1e30f,-1e30f,-1e30f};
  #pragma unroll
  for(int t=0;t<16;t++)
    #pragma unroll
    for(int e=0;e<4;e++) mx[e] = fmaxf(mx[e], acc[t][e]*SCALE);
  #pragma unroll
  for(int s=1;s<16;s<<=1)
    #pragma unroll
    for(int e=0;e<4;e++) mx[e] = fmaxf(mx[e], __shfl_xor(mx[e], s));
  float sm[4] = {0.f,0.f,0.f,0.f};
  #pragma unroll
  for(int t=0;t<16;t++)
    #pragma unroll
    for(int e=0;e<4;e++){ float p = expf(acc[t][e]*SCALE - mx[e]); acc[t][e]=p; sm[e]+=p; }
  #pragma unroll
  for(int s=1;s<16;s<<=1)
    #pragma unroll
    for(int e=0;e<4;e++) sm[e] += __shfl_xor(sm[e], s);
  float inv[4];
  #pragma unroll
  for(int e=0;e<4;e++) inv[e] = 1.f/sm[e];
  __syncthreads();
  u16* PS = SKL;
  #pragma unroll
  for(int t=0;t<16;t++)
    #pragma unroll
    for(int e=0;e<4;e++)
      PS[(w*16 + q*4 + e)*256 + t*16 + lr] = f2b(acc[t][e]*inv[e]);
  __syncthreads();
  f4 acc2[4] = {};
  #pragma unroll
  for(int ks=0;ks<8;ks++){
    bf8 af = *(const bf8*)&PS[(w*16+lr)*256 + ks*32 + q*8];
    #pragma unroll
    for(int t=0;t<4;t++){
      bf8 bf_ = *(const bf8*)&SZV[(t*16+lr)*256 + ks*32 + q*8];
      acc2[t] = __builtin_amdgcn_mfma_f32_16x16x32_bf16(af, bf_, acc2[t], 0,0,0);
    }
  }
  #pragma unroll
  for(int t=0;t<4;t++)
    #pragma unroll
    for(int r=0;r<4;r++){
      int gm = m0 + w*16 + q*4 + r;
      int gd = t*16 + lr;
      Qc[((long)b*NP + gm)*512 + h*64 + gd] = acc2[t][r];
    }
}

// ======== softmax: wave per row, 256 cols, fp32 ========
__global__ __launch_bounds__(256)
void k_smw32(float* __restrict__ X){
  long row = (long)blockIdx.x*4 + (threadIdx.x>>6);
  int lane = threadIdx.x & 63;
  float* p = X + row*256;
  float4 v = *(float4*)&p[lane*4];
  float m = fmaxf(fmaxf(v.x,v.y),fmaxf(v.z,v.w));
  for(int s=32;s;s>>=1) m = fmaxf(m, __shfl_xor(m, s));
  float e0=expf(v.x-m), e1=expf(v.y-m), e2=expf(v.z-m), e3=expf(v.w-m);
  float sum = e0+e1+e2+e3;
  for(int s=32;s;s>>=1) sum += __shfl_xor(sum, s);
  float inv = 1.f/sum;
  float4 o = {e0*inv, e1*inv, e2*inv, e3*inv};
  *(float4*)&p[lane*4] = o;
}

// ======== softmax: block per row, 4352 cols, register-resident bf16 ========
__global__ __launch_bounds__(256)
void k_smb16(u16* __restrict__ X){
  u16* p = X + (long)blockIdx.x*4352;
  int tid=threadIdx.x, lane=tid&63, w=tid>>6;
  __shared__ float xw[4], sw[4];
  float e[17];
  float m = -1e30f;
  #pragma unroll
  for(int i=0;i<17;i++){ e[i] = b2f(p[tid + i*256]); m = fmaxf(m, e[i]); }
  for(int s=32;s;s>>=1) m = fmaxf(m, __shfl_xor(m, s));
  if(lane==0) xw[w] = m;
  __syncthreads();
  m = fmaxf(fmaxf(xw[0],xw[1]), fmaxf(xw[2],xw[3]));
  float sum = 0.f;
  #pragma unroll
  for(int i=0;i<17;i++){ e[i] = expf(e[i]-m); sum += e[i]; }
  for(int s=32;s;s>>=1) sum += __shfl_xor(sum, s);
  if(lane==0) sw[w] = sum;
  __syncthreads();
  sum = sw[0]+sw[1]+sw[2]+sw[3];
  float inv = 1.f/sum;
  #pragma unroll
  for(int i=0;i<17;i++) p[tid + i*256] = f2b(e[i]*inv);
}

// weight transpose+convert: in fp32 [K][N] -> out bf16 [N][K]
__global__ void k_wT(const float* __restrict__ in, u16* __restrict__ out, int K, int N){
  int n0=blockIdx.x*32, k0=blockIdx.y*32, tid=threadIdx.x;
  __shared__ float T[32][33];
  int lr=tid&31, lc=tid>>5;
  #pragma unroll
  for(int p=0;p<4;p++) T[lc+8*p][lr] = in[(long)(k0+lc+8*p)*N + n0+lr];
  __syncthreads();
  #pragma unroll
  for(int p=0;p<4;p++) out[(long)(n0+lc+8*p)*K + k0+lr] = f2b(T[lr][lc+8*p]);
}

// v^T: qkvb16 v-section [NP][64] per (b,h) -> vT [b][h][64][NP]
__global__ __launch_bounds__(256)
void k_vT(const u16* __restrict__ qkv16, u16* __restrict__ vT){
  int t0=blockIdx.x*64, h=blockIdx.y, b=blockIdx.z, tid=threadIdx.x;
  __shared__ u16 T[64][72];
  const u16* src = qkv16 + (long)b*NP*1536 + 1024 + h*64;
  for(int s=0;s<2;s++){
    int idx=tid+s*256; int row=idx>>3, c8=(idx&7)*8;
    *(us8*)&T[row][c8] = *(const us8*)&src[(long)(t0+row)*1536 + c8];
  }
  __syncthreads();
  u16* dst = vT + ((long)(b*8+h)*64)*NP;
  int d = tid>>2, j0=(tid&3)*16;
  us8 v0,v1;
  #pragma unroll
  for(int jj=0;jj<8;jj++){ v0[jj]=T[j0+jj][d]; v1[jj]=T[j0+8+jj][d]; }
  *(us8*)&dst[(long)d*NP + t0 + j0]     = v0;
  *(us8*)&dst[(long)d*NP + t0 + j0 + 8] = v1;
}

__global__ void k_cvt16(const float* __restrict__ in, u16* __restrict__ out, long n){
  long i = (long)blockIdx.x*256 + threadIdx.x;
  if(i<n) out[i] = f2b(in[i]);
}

__global__ void k_zero(float* __restrict__ p, long n){
  long i = (long)blockIdx.x*256 + threadIdx.x;
  if(i<n) p[i] = 0.f;
}

__global__ void k_cls(const float* __restrict__ cls, float* __restrict__ seq){
  int b = blockIdx.x;
  seq[(long)b*NTOK*EMB + threadIdx.x] = cls[threadIdx.x];
}

// LayerNorm of seq into xpb bf16 with 255 zero rows at front
__global__ void k_ln_pad(const float* __restrict__ seq, u16* __restrict__ xp,
                         const float* __restrict__ g, const float* __restrict__ bb){
  int b = blockIdx.y, i = blockIdx.x, tid = threadIdx.x;
  u16* out = xp + ((long)b*NP + i)*EMB;
  if(i < PADF){ out[tid]=0; out[tid+256]=0; return; }
  const float* x = seq + ((long)b*NTOK + (i-PADF))*EMB;
  float v0 = x[tid], v1 = x[tid+256];
  __shared__ float red[256];
  red[tid]=v0+v1; __syncthreads();
  for(int s=128;s>0;s>>=1){ if(tid<s) red[tid]+=red[tid+s]; __syncthreads(); }
  float mu = red[0]*(1.0f/512.0f); __syncthreads();
  float d0=v0-mu, d1=v1-mu;
  red[tid]=d0*d0+d1*d1; __syncthreads();
  for(int s=128;s>0;s>>=1){ if(tid<s) red[tid]+=red[tid+s]; __syncthreads(); }
  float rstd = rsqrtf(red[0]*(1.0f/512.0f) + 1e-5f);
  out[tid]     = f2b(d0*rstd*g[tid]     + bb[tid]);
  out[tid+256] = f2b(d1*rstd*g[tid+256] + bb[tid+256]);
}

__global__ void k_landmarks(const u16* __restrict__ qkv, u16* __restrict__ q_l, u16* __restrict__ k_l){
  int j = blockIdx.x, h = blockIdx.y, b = blockIdx.z, d = threadIdx.x;
  const u16* base = qkv + (long)b*NP*1536 + h*64 + d;
  float sq=0.f, sk=0.f;
  for(int l=0;l<17;l++){
    long row = (long)(j*17+l)*1536;
    sq += b2f(base[row]);
    sk += b2f(base[row+512]);
  }
  long o = (((long)b*HEADS + h)*LM + j)*DH + d;
  q_l[o] = f2b(sq * (SCALE/17.0f));
  k_l[o] = f2b(sk * (1.0f/17.0f));
}

__global__ void k_pinv_norm(const float* __restrict__ A2, float* __restrict__ rmax, float* __restrict__ cmax){
  int z = blockIdx.x, tid = threadIdx.x;
  const float* X = A2 + (long)z*65536;
  float rs=0.f, cs=0.f;
  for(int j=0;j<256;j++){ rs += fabsf(X[tid*256+j]); cs += fabsf(X[j*256+tid]); }
  __shared__ float r1[256], r2[256];
  r1[tid]=rs; r2[tid]=cs; __syncthreads();
  for(int s=128;s>0;s>>=1){ if(tid<s){ r1[tid]=fmaxf(r1[tid],r1[tid+s]); r2[tid]=fmaxf(r2[tid],r2[tid+s]); } __syncthreads(); }
  if(tid==0){ rmax[z]=r1[0]; cmax[z]=r2[0]; }
}

__global__ void k_pair_init(const float* __restrict__ att2,
    const float* __restrict__ rmax, const float* __restrict__ cmax,
    u16* __restrict__ Xh, u16* __restrict__ Xl,
    u16* __restrict__ Zh, u16* __restrict__ Zl,
    u16* __restrict__ Zth, u16* __restrict__ Ztl)
{
  long zo = (long)blockIdx.z*65536;
  int i0 = blockIdx.y*64, j0 = blockIdx.x*64;
  float rm=0.f, cm=0.f;
  for(int t=0;t<16;t++){ rm=fmaxf(rm,rmax[t]); cm=fmaxf(cm,cmax[t]); }
  float inv = 1.0f/(rm*cm);
  __shared__ float T[64][68];
  int tid = threadIdx.x;
  int li = tid>>2, jc = (tid&3)*16;
  #pragma unroll
  for(int u=0;u<4;u++){
    float4 v = *(const float4*)&att2[zo + (long)(i0+li)*256 + j0 + jc + u*4];
    T[li][jc+u*4]=v.x; T[li][jc+u*4+1]=v.y; T[li][jc+u*4+2]=v.z; T[li][jc+u*4+3]=v.w;
    long o = zo + (long)(i0+li)*256 + j0 + jc + u*4;
    float vv[4] = {v.x,v.y,v.z,v.w};
    us4 xh, xl, zth, ztl;
    #pragma unroll
    for(int c=0;c<4;c++){
      u16 h = f2b(vv[c]); xh[c]=h; xl[c]=f2b(vv[c]-b2f(h));
      float zt = vv[c]*inv;
      u16 h2 = f2b(zt); zth[c]=h2; ztl[c]=f2b(zt-b2f(h2));
    }
    *(us4*)&Xh[o]=xh; *(us4*)&Xl[o]=xl; *(us4*)&Zth[o]=zth; *(us4*)&Ztl[o]=ztl;
  }
  __syncthreads();
  int lj = tid>>2, ic = (tid&3)*16;
  #pragma unroll
  for(int r=0;r<16;r++){
    float x = T[ic+r][lj]*inv;
    u16 h = f2b(x);
    long o = zo + (long)(j0+lj)*256 + i0 + ic + r;
    Zh[o]=h; Zl[o]=f2b(x-b2f(h));
  }
}

// res conv + fused bf16 convert: Qc16 = bf16(Qc + dwconv(v))
__global__ __launch_bounds__(256)
void k_rconv(const u16* __restrict__ qkv16, const float* __restrict__ resk,
             const float* __restrict__ Qin, u16* __restrict__ Qo16){
  int t0 = blockIdx.x*64, h = blockIdx.y, b = blockIdx.z;
  __shared__ float V[96*64];
  const u16* vb = qkv16 + (long)b*NP*1536 + 1024 + h*64;
  int tid = threadIdx.x;
  #pragma unroll
  for(int s=0;s<3;s++){
    int idx = tid + s*256;
    int row = idx>>3, c8 = (idx&7)*8;
    int p = t0 - 16 + row;
    if(p>=0 && p<NP){
      us8 v = *(const us8*)&vb[(long)p*1536 + c8];
      #pragma unroll
      for(int jj=0;jj<8;jj++) V[row*64+c8+jj] = b2f(v[jj]);
    } else {
      #pragma unroll
      for(int jj=0;jj<8;jj++) V[row*64+c8+jj] = 0.f;
    }
  }
  __syncthreads();
  int d = tid&63, lt = (tid>>6)*16;
  float acc[16] = {};
  #pragma unroll
  for(int s=0;s<48;s++){
    float val = V[(lt+s)*64 + d];
    #pragma unroll
    for(int j=0;j<16;j++){
      int tap = s - j;
      if(tap>=0 && tap<33) acc[j] += resk[h*33+tap]*val;
    }
  }
  #pragma unroll
  for(int j=0;j<16;j++){
    long idx = ((long)b*NP + t0 + lt + j)*EMB + h*64 + d;
    Qo16[idx] = f2b(Qin[idx] + acc[j]);
  }
}

// PPEG: 64-ch groups, 4 rows x 64 ch per block, x-split 2; grid (32, 8, 2)
__global__ __launch_bounds__(256)
void k_ppeg(const float* __restrict__ seq, float* __restrict__ out,
    const float* __restrict__ w7,const float* __restrict__ b7,
    const float* __restrict__ w5,const float* __restrict__ b5,
    const float* __restrict__ w3,const float* __restrict__ b3){
  int b = blockIdx.z, cg = blockIdx.y;
  int rp = blockIdx.x>>1, xs = blockIdx.x&1;
  int ch0 = cg*64;
  __shared__ float s7[64*49], s5[64*25], s3[64*9], sbias[64];
  int tid = threadIdx.x;
  for(int i=tid;i<64*49;i+=256) s7[i] = w7[ch0*49+i];
  for(int i=tid;i<64*25;i+=256) s5[i] = w5[ch0*25+i];
  for(int i=tid;i<64*9;i+=256)  s3[i] = w3[ch0*9+i];
  if(tid<64) sbias[tid] = b7[ch0+tid]+b5[ch0+tid]+b3[ch0+tid];
  if(cg==0 && blockIdx.x==0){
    out[(long)b*NTOK*EMB + tid]       = seq[(long)b*NTOK*EMB + tid];
    out[(long)b*NTOK*EMB + 256 + tid] = seq[(long)b*NTOK*EMB + 256 + tid];
  }
  __syncthreads();
  int c = tid & 63;
  int y = rp*4 + (tid>>6);
  const float* sbase = seq + (long)b*NTOK*EMB + EMB + (ch0 + c);
  float* obase = out + (long)b*NTOK*EMB + EMB + (ch0 + c);
  const float* W7 = &s7[c*49];
  const float* W5 = &s5[c*25];
  const float* W3 = &s3[c*9];
  float bsum = sbias[c];
  for(int xc=0;xc<4;xc++){
    int xb = xs*32 + xc*8;
    float acc[8];
    #pragma unroll
    for(int j=0;j<8;j++) acc[j] = sbase[(long)(y*64+xb+j)*EMB] + bsum;
    #pragma unroll
    for(int dy=-3;dy<=3;dy++){
      int yy = y+dy;
      if(yy<0||yy>=64) continue;
      float v[14];
      #pragma unroll
      for(int u=0;u<14;u++){
        int xx = xb + u - 3;
        v[u] = (xx>=0 && xx<64) ? sbase[(long)(yy*64+xx)*EMB] : 0.f;
      }
      #pragma unroll
      for(int dx=-3;dx<=3;dx++){
        float wsum = W7[(dy+3)*7+(dx+3)];
        if(dy>=-2&&dy<=2&&dx>=-2&&dx<=2) wsum += W5[(dy+2)*5+(dx+2)];
        if(dy>=-1&&dy<=1&&dx>=-1&&dx<=1) wsum += W3[(dy+1)*3+(dx+1)];
        #pragma unroll
        for(int j=0;j<8;j++) acc[j] += v[j+dx+3]*wsum;
      }
    }
    #pragma unroll
    for(int j=0;j<8;j++) obase[(long)(y*64+xb+j)*EMB] = acc[j];
  }
}

__global__ void k_final_ln(const float* __restrict__ seq, const float* __restrict__ g,
                           const float* __restrict__ bb, float* __restrict__ out){
  int b = blockIdx.x, tid = threadIdx.x;
  const float* x = seq + (long)b*NTOK*EMB;
  float v0 = x[tid], v1 = x[tid+256];
  __shared__ float red[256];
  red[tid]=v0+v1; __syncthreads();
  for(int s=128;s>0;s>>=1){ if(tid<s) red[tid]+=red[tid+s]; __syncthreads(); }
  float mu = red[0]*(1.0f/512.0f); __syncthreads();
  float d0=v0-mu, d1=v1-mu;
  red[tid]=d0*d0+d1*d1; __syncthreads();
  for(int s=128;s>0;s>>=1){ if(tid<s) red[tid]+=red[tid+s]; __syncthreads(); }
  float rstd = rsqrtf(red[0]*(1.0f/512.0f) + 1e-5f);
  out[b*512+tid]     = d0*rstd*g[tid]     + bb[tid];
  out[b*512+tid+256] = d1*rstd*g[tid+256] + bb[tid+256];
}

// ---------------- host ----------------
extern "C" void kernel_launch(void* const* d_in, const int* in_sizes, int n_in,
                              void* d_out, int out_size, void* d_ws, size_t ws_size,
                              hipStream_t stream) {
  const float* in[24];
  for(int i=0;i<24;i++) in[i] = (const float*)d_in[i];

  float* W = (float*)d_ws;
  size_t off = 0;
  float* seqA = W+off; off += 4195328;        // 2*4097*512
  float* seqB = W+off; off += 4195328;
  float* att2 = W+off; off += 1048576;        // 16*65536
  float* Qc   = W+off; off += 4456448;        // 2*4352*512
  float* avbT = W+off; off += 262144;         // 16*64*256
  u16* xpb    = (u16*)(W+off); off += 2228224;  // 2*4352*512 u16
  u16* qkvb16 = (u16*)(W+off); off += 6684672;  // 2*4352*1536 u16
  u16* vT16   = (u16*)(W+off); off += 2228224;
  u16* q_l16  = (u16*)(W+off); off += 131072;   // 16*256*64 u16
  u16* k_l16  = (u16*)(W+off); off += 131072;
  u16* sc16   = (u16*)(W+off); off += 8912896;  // 16*256*4352 u16
  u16* avbT16 = (u16*)(W+off); off += 131072;
  u16* zavT16 = (u16*)(W+off); off += 131072;
  u16* Qc16   = (u16*)(W+off); off += 2228224;
  u16* qkvwT1 = (u16*)(W+off); off += 393216;   // 1536*512 u16
  u16* qkvwT2 = (u16*)(W+off); off += 393216;
  u16* outwT1 = (u16*)(W+off); off += 131072;   // 512*512 u16
  u16* outwT2 = (u16*)(W+off); off += 131072;
  u16* pairs  = (u16*)(W+off); off += 9437184;  // 18*16*65536 u16
  float* rmax = W+off; off += 16;
  float* cmax = W+off; off += 16;
  if (ws_size < off*sizeof(float)) return;

  u16* h16   = sc16;                  // aliased (sc16 written later)
  u16* wfc1T = sc16 + 8388608;

  const long PB = 1048576;  // 16*65536
  u16 *Xh=pairs, *Xl=pairs+PB;
  u16 *Z0h=pairs+2*PB, *Z0l=pairs+3*PB, *Z0th=pairs+4*PB, *Z0tl=pairs+5*PB;
  u16 *Z1h=pairs+6*PB, *Z1l=pairs+7*PB, *Z1th=pairs+8*PB, *Z1tl=pairs+9*PB;
  u16 *Ph=pairs+10*PB, *Pl=pairs+11*PB;
  u16 *Tth=pairs+12*PB, *Ttl=pairs+13*PB;
  u16 *Uth=pairs+14*PB, *Utl=pairs+15*PB;
  u16 *Vth=pairs+16*PB, *Vtl=pairs+17*PB;

  // weight conversions/transposes
  k_cvt16<<<32768,256,0,stream>>>(in[0], h16, 8388608L);
  k_wT<<<dim3(16,32),256,0,stream>>>(in[1],  wfc1T, 1024, 512);
  k_wT<<<dim3(48,16),256,0,stream>>>(in[6],  qkvwT1, 512, 1536);
  k_wT<<<dim3(48,16),256,0,stream>>>(in[18], qkvwT2, 512, 1536);
  k_wT<<<dim3(16,16),256,0,stream>>>(in[7],  outwT1, 512, 512);
  k_wT<<<dim3(16,16),256,0,stream>>>(in[19], outwT2, 512, 512);

  // fc1 + cls
  k_g128<0><<<dim3(4,32,2),256,0,stream>>>(h16, wfc1T, seqA+EMB, nullptr,
      1024, 1024,1024,512, 4194304L,0, 0,0, (long)NTOK*EMB,0, 1, 1.0f, in[2], 1, 0, 4, 1);
  k_cls<<<2,512,0,stream>>>(in[3], seqA);

  auto attention = [&](float* seq, const float* lng,const float* lnb,
                       const u16* qkvwT, const u16* outwT, const float* outb, const float* resk){
    k_ln_pad<<<dim3(NP,2),256,0,stream>>>(seq, xpb, lng, lnb);
    k_g128<2><<<dim3(12,34,2),256,0,stream>>>(xpb, qkvwT, nullptr, qkvb16,
        512, 512,512,1536, (long)NP*512,0, 0,0, (long)NP*1536,0, 1, 1.0f, nullptr, 0, 0, 12, 1);
    k_landmarks<<<dim3(LM,HEADS,2),64,0,stream>>>(qkvb16, q_l16, k_l16);
    k_vT<<<dim3(68,8,2),256,0,stream>>>(qkvb16, vT16);
    // attn2 = softmax(q_l @ k_l^T)  (fp32 scores for pinv)
    k_g128<0><<<dim3(2,2,16),256,0,stream>>>(q_l16, k_l16, att2, nullptr,
        64, 64,64,256, 0,16384, 0,16384, 0,65536, 16, 1.0f, nullptr, 0, 0, 2, 1);
    k_smw32<<<1024,256,0,stream>>>(att2);
    // pinv on bf16 pairs
    k_pinv_norm<<<16,256,0,stream>>>(att2, rmax, cmax);
    k_pair_init<<<dim3(4,4,16),256,0,stream>>>(att2, rmax, cmax, Xh,Xl, Z0h,Z0l, Z0th,Z0tl);
    dim3 pgrid(4,8,16);
    for(int it=0; it<6; it++){
      u16 *Zh_=(it&1)?Z1h:Z0h, *Zl_=(it&1)?Z1l:Z0l, *Zth_=(it&1)?Z1th:Z0th, *Ztl_=(it&1)?Z1tl:Z0tl;
      u16 *Nh_=(it&1)?Z0h:Z1h, *Nl_=(it&1)?Z0l:Z1l, *Nth_=(it&1)?Z0th:Z1th, *Ntl_=(it&1)?Z0tl:Z1tl;
      k_pg3<<<pgrid,256,0,stream>>>(Xh,Xl, Zth_,Ztl_, Ph,Pl,1.0f,0.f, Tth,Ttl,-1.0f,7.f);
      k_pg3<<<pgrid,256,0,stream>>>(Ph,Pl, Tth,Ttl, nullptr,nullptr,0.f,0.f, Uth,Utl,-1.0f,15.f);
      k_pg3<<<pgrid,256,0,stream>>>(Ph,Pl, Uth,Utl, nullptr,nullptr,0.f,0.f, Vth,Vtl,-1.0f,13.f);
      if(it<5) k_pg3<<<pgrid,256,0,stream>>>(Zh_,Zl_, Vth,Vtl, Nh_,Nl_,0.25f,0.f, Nth_,Ntl_,0.25f,0.f);
      else     k_pg3<<<pgrid,256,0,stream>>>(Zh_,Zl_, Vth,Vtl, Nh_,Nl_,0.25f,0.f, nullptr,nullptr,0.f,0.f);
    }
    // attn3 scores = q_l @ k^T -> sc16 (bf16)
    k_g128<2><<<dim3(34,2,16),256,0,stream>>>(q_l16, qkvb16+512, nullptr, sc16,
        64, 64,1536,4352, 131072L,16384, (long)NP*1536,64, 8L*LM*NP,(long)LM*NP, 8, 1.0f, nullptr, 0, 0, 34, 1);
    k_smb16<<<4096,256,0,stream>>>(sc16);
    // avbT = v^T @ attn3_sm^T (split-K atomic)
    k_zero<<<1024,256,0,stream>>>(avbT, 262144L);
    k_g64<3><<<dim3(4*17,1,16),256,0,stream>>>(vT16, sc16, avbT, nullptr,
        4352, 4352,4352,256, 2228224L,278528L, 8L*LM*NP,(long)LM*NP, 131072L,16384L, 8, 1.0f, 4, 17);
    k_cvt16<<<1024,256,0,stream>>>(avbT, avbT16, 262144L);
    // zavT = avbT @ Z^T  -> bf16
    k_g64<2><<<dim3(4,1,16),256,0,stream>>>(avbT16, Z0h, nullptr, zavT16,
        256, 256,256,256, 0,16384L, 0,65536L, 0,16384L, 16, 1.0f, 4, 1);
    // fused attn1: scores + softmax + @zav -> Qc
    k_att1<<<dim3(68,16),256,0,stream>>>(qkvb16, k_l16, zavT16, Qc);
    // res conv fused with bf16 convert
    k_rconv<<<dim3(68,8,2),256,0,stream>>>(qkvb16, resk, Qc, Qc16);
    // out proj + residual add into seq (split-K=2, atomic, bias on kc==0)
    k_g128<4><<<dim3(8,34,2),256,0,stream>>>(Qc16, outwT, seq, nullptr,
        512, 512,512,512, (long)NP*512,0, 0,0, (long)NTOK*EMB,0, 1, 1.0f, outb, 0, PADF, 4, 2);
  };

  attention(seqA, in[4], in[5], qkvwT1, outwT1, in[8], in[9]);
  k_ppeg<<<dim3(32,8,2),256,0,stream>>>(seqA, seqB, in[10],in[11],in[12],in[13],in[14],in[15]);
  attention(seqB, in[16], in[17], qkvwT2, outwT2, in[20], in[21]);
  k_final_ln<<<2,256,0,stream>>>(seqB, in[22], in[23], (float*)d_out);
}